// Round 2
// baseline (427.155 us; speedup 1.0000x reference)
//
#include <hip/hip_runtime.h>
#include <math.h>

#define EPSF 1e-8f

__device__ __forceinline__ int PADi(int i) { return i + (i >> 5); }

template<int NV>
__device__ __forceinline__ void block_sum_batch(float* vals, float* red, int tid) {
  const int lane = tid & 63, wid = tid >> 6;
#pragma unroll
  for (int i = 0; i < NV; ++i) {
    float v = vals[i];
#pragma unroll
    for (int d = 32; d >= 1; d >>= 1) v += __shfl_down(v, d, 64);
    if (lane == 0) red[wid * NV + i] = v;
  }
  __syncthreads();
#pragma unroll
  for (int i = 0; i < NV; ++i)
    vals[i] = red[i] + red[NV + i] + red[2 * NV + i] + red[3 * NV + i];
  __syncthreads();
}

// block-wide exclusive prefix of per-thread chunk sums
__device__ __forceinline__ float block_scan_excl(float cs, float* red, int tid) {
  const int lane = tid & 63, wid = tid >> 6;
  float s = cs;
#pragma unroll
  for (int d = 1; d < 64; d <<= 1) {
    float t = __shfl_up(s, d, 64);
    if (lane >= d) s += t;
  }
  if (lane == 63) red[wid] = s;
  __syncthreads();
  float woff = 0.f;
#pragma unroll
  for (int w = 0; w < 4; ++w) woff += (w < wid) ? red[w] : 0.f;
  __syncthreads();
  return woff + s - cs;
}

// in-place radix-4 DIF stage; 256 butterflies, output digit-reversed (never reordered).
// Twiddles on the fly via v_sin/v_cos (1 trans op each) — no table, no table LDS reads.
template<int LEN>
__device__ __forceinline__ void fft_stage(float* fr, float* fi, int tid) {
  constexpr int H = LEN >> 2;
  const int g = tid / H;
  const int j = tid & (H - 1);
  const int base = g * LEN + j;
  const int i0 = PADi(base), i1 = PADi(base + H), i2 = PADi(base + 2 * H), i3 = PADi(base + 3 * H);
  float a0r = fr[i0], a0i = fi[i0];
  float a1r = fr[i1], a1i = fi[i1];
  float a2r = fr[i2], a2i = fi[i2];
  float a3r = fr[i3], a3i = fi[i3];
  float t0r = a0r + a2r, t0i = a0i + a2i;
  float t1r = a0r - a2r, t1i = a0i - a2i;
  float t2r = a1r + a3r, t2i = a1i + a3i;
  float t3r = a1r - a3r, t3i = a1i - a3i;
  float y0r = t0r + t2r, y0i = t0i + t2i;
  float y1r = t1r + t3i, y1i = t1i - t3r;   // (t1 - i*t3)
  float y2r = t0r - t2r, y2i = t0i - t2i;
  float y3r = t1r - t3i, y3i = t1i + t3r;   // (t1 + i*t3)
  fr[i0] = y0r; fi[i0] = y0i;
  if constexpr (LEN == 4) {
    // identity twiddles on the last stage
    fr[i1] = y1r; fi[i1] = y1i;
    fr[i2] = y2r; fi[i2] = y2i;
    fr[i3] = y3r; fi[i3] = y3i;
  } else {
    constexpr float W = -6.283185307179586f * (float)(1024 / LEN) * (1.f / 1024.f);
    const float a1 = W * (float)j;
    const float a2 = a1 + a1;
    const float a3 = a2 + a1;
    const float c1 = __cosf(a1), s1 = __sinf(a1);
    const float c2 = __cosf(a2), s2 = __sinf(a2);
    const float c3 = __cosf(a3), s3 = __sinf(a3);
    fr[i1] = y1r * c1 - y1i * s1;  fi[i1] = y1r * s1 + y1i * c1;
    fr[i2] = y2r * c2 - y2i * s2;  fi[i2] = y2r * s2 + y2i * c2;
    fr[i3] = y3r * c3 - y3i * s3;  fi[i3] = y3r * s3 + y3i * c3;
  }
}

__global__ void __launch_bounds__(256, 8)
sr_kernel(const float* __restrict__ x,
          const float* __restrict__ ln_w, const float* __restrict__ ln_b,
          const float* __restrict__ w1, const float* __restrict__ b1,
          const float* __restrict__ w2, const float* __restrict__ b2,
          float* __restrict__ out, int B)
{
  __shared__ float fr[1056], fi[1056];
  __shared__ float ps[1057];          // padded prefix array: PADi indexing
  __shared__ float red[64];

  const int tid  = threadIdx.x;
  const int lane = tid & 63;
  const int wid  = tid >> 6;
  const int row  = blockIdx.x;
  if (row >= B) return;
  const float* __restrict__ xr = x + (size_t)row * 1024;

  // ---- load row ----
  const int c0 = tid * 4;
  const float4 v4 = *reinterpret_cast<const float4*>(xr + c0);
  fr[PADi(c0 + 0)] = v4.x; fr[PADi(c0 + 1)] = v4.y;
  fr[PADi(c0 + 2)] = v4.z; fr[PADi(c0 + 3)] = v4.w;
  fi[PADi(c0 + 0)] = 0.f; fi[PADi(c0 + 1)] = 0.f;
  fi[PADi(c0 + 2)] = 0.f; fi[PADi(c0 + 3)] = 0.f;
  __syncthreads();

  // ---- prefix sum of x -> ps (padded) ----
  const float cs4 = v4.x + v4.y + v4.z + v4.w;
  const float excl = block_scan_excl(cs4, red, tid);
  ps[PADi(c0 + 1)] = excl + v4.x;
  ps[PADi(c0 + 2)] = excl + v4.x + v4.y;
  ps[PADi(c0 + 3)] = excl + v4.x + v4.y + v4.z;
  ps[PADi(c0 + 4)] = excl + cs4;
  if (tid == 0) ps[0] = 0.f;

  // ---- per-thread stats from registers/LDS (x pristine in fr) ----
  const float x0 = fr[PADi(0)];
  const float xl = fr[PADi(1023)];
  float vv[14];
  vv[0] = v4.x; vv[1] = v4.y; vv[2] = v4.z; vv[3] = v4.w;
#pragma unroll
  for (int j = 4; j < 14; ++j) {
    int idx = c0 + j;
    vv[j] = (idx < 1024) ? fr[PADi(idx)] : 0.f;
  }
  float vals[16];
  vals[0] = vv[0]*vv[0] + vv[1]*vv[1] + vv[2]*vv[2] + vv[3]*vv[3];  // sum x^2
  vals[1] = vv[0] - vv[1] + vv[2] - vv[3];                           // sum (-1)^n x -> X[512]
#pragma unroll
  for (int k = 1; k <= 10; ++k) {
    float r = 0.f;
#pragma unroll
    for (int j = 0; j < 4; ++j) r += vv[j] * vv[j + k];
    vals[1 + k] = r;                                                 // raw lag product R_k
  }
  __syncthreads();   // ps fully written

  // ---- trend / kpss partials (from prefix sums only) ----
  float trv[4], str = 0.f, str2 = 0.f;
#pragma unroll
  for (int j = 0; j < 4; ++j) {
    int i = c0 + j;
    int a = i - 12; a = a < 0 ? 0 : a;
    int b = i + 12; b = b > 1023 ? 1023 : b;
    float s = ps[PADi(b + 1)] - ps[PADi(a)];
    if (i < 12)   s += (float)(12 - i) * x0;
    if (i > 1011) s += (float)(i - 1011) * xl;
    float t = s * (1.f / 25.f);
    trv[j] = t; str += t; str2 += t * t;
  }
  const float texcl = block_scan_excl(trv[0] + trv[1] + trv[2] + trv[3], red, tid);
  float run = texcl, sc = 0.f, sc2 = 0.f;
#pragma unroll
  for (int j = 0; j < 4; ++j) {
    run += trv[j];
    float c = ps[PADi(c0 + j + 1)] - run;   // cumsum(resid)[i]
    sc += c; sc2 += c * c;
  }
  vals[12] = str; vals[13] = str2; vals[14] = sc; vals[15] = sc2;
  block_sum_batch<16>(vals, red, tid);
  const float SUMSQ = vals[0];
  const float ALT   = vals[1];
  const float SUMX  = ps[PADi(1024)];

  // ---- FFT (radix-4 DIF, in place, order-free) ----
  fft_stage<1024>(fr, fi, tid); __syncthreads();
  fft_stage<256>(fr, fi, tid);  __syncthreads();
  fft_stage<64>(fr, fi, tid);   __syncthreads();
  fft_stage<16>(fr, fi, tid);   __syncthreads();
  fft_stage<4>(fr, fi, tid);    __syncthreads();

  // ---- psd reductions over full spectrum ----
  float pq[4], psum = 0.f, pmax = 0.f;
#pragma unroll
  for (int q = 0; q < 4; ++q) {
    int p = tid + q * 256;
    float rr = fr[PADi(p)], ii = fi[PADi(p)];
    float pp = fmaxf(rr * rr + ii * ii, EPSF);
    pq[q] = pp; psum += pp; pmax = fmaxf(pmax, pp);
  }
#pragma unroll
  for (int d = 32; d >= 1; d >>= 1) {
    psum += __shfl_down(psum, d, 64);
    pmax = fmaxf(pmax, __shfl_down(pmax, d, 64));
  }
  if (lane == 0) { red[wid] = psum; red[4 + wid] = pmax; }
  __syncthreads();
  const float SFULL = red[0] + red[1] + red[2] + red[3];
  const float PMAX  = fmaxf(fmaxf(red[4], red[5]), fmaxf(red[6], red[7]));
  __syncthreads();
  const float p0b   = fmaxf(SUMX * SUMX, EPSF);   // |X[0]|^2 exactly
  const float p512b = fmaxf(ALT * ALT, EPSF);     // |X[512]|^2 exactly
  const float Sr    = 0.5f * (SFULL + p0b + p512b);   // rfft psd sum
  const float invS  = 1.f / Sr;
  float ts[1]; ts[0] = 0.f;
#pragma unroll
  for (int q = 0; q < 4; ++q) {
    float pn = pq[q] * invS;
    ts[0] += pn * __logf(pn + EPSF);
  }
  block_sum_batch<1>(ts, red, tid);
  const float g0   = (p0b * invS)   * __logf(p0b * invS + EPSF);
  const float g512 = (p512b * invS) * __logf(p512b * invS + EPSF);
  const float ent  = -0.5f * (ts[0] + g0 + g512);

  // ---- features ----
  const float m = SUMX * (1.f / 1024.f);
  const float den = SUMSQ - 1024.f * m * m + EPSF;
  const float invden = 1.f / den;
  float acf1 = 0.f, acf2 = 0.f, lbq = 0.f;
#pragma unroll
  for (int k = 1; k <= 10; ++k) {
    float num = vals[1 + k]
              - m * (ps[PADi(1024 - k)] + (SUMX - ps[PADi(k)]))
              + (float)(1024 - k) * m * m;
    float a = fminf(fmaxf(num * invden, -1.f), 1.f);
    if (k == 1) acf1 = a;
    else if (k == 2) acf2 = a;
    lbq += a * a;
  }
  const float spent = fminf(fmaxf(ent / (__logf(513.f + EPSF) + EPSF), 0.f), 1.f);
  const float peak  = fminf(fmaxf(PMAX / (Sr + EPSF), 0.f), 1.f);
  const float R1 = vals[2];
  const float phi = fminf(fmaxf(R1 / ((SUMSQ - xl * xl) + EPSF), -1.f), 1.f);
  const float invn = 1.f / 1023.f;
  const float sum_d2 = 2.f * SUMSQ - x0 * x0 - xl * xl - 2.f * R1;
  const float md = (xl - x0) * invn;
  const float diff_var = sum_d2 * invn - md * md;
  const float STR = vals[12], STR2 = vals[13], SC = vals[14], SC2 = vals[15];
  const float tstr = STR2 * (1.f / 1024.f) - (STR * (1.f / 1024.f)) * (STR * (1.f / 1024.f));
  const float varx = SUMSQ * (1.f / 1024.f) - m * m;
  const float mc = SC * (1.f / 1024.f);
  const float kpss = (SC2 * (1.f / 1024.f) - mc * mc) / (varx + 1e-8f);

  float f[9] = {acf1, acf2, spent, phi, diff_var, tstr, kpss, lbq, peak};
  float fm = 0.f;
#pragma unroll
  for (int d = 0; d < 9; ++d) fm += f[d];
  fm *= (1.f / 9.f);
  float fv = 0.f;
#pragma unroll
  for (int d = 0; d < 9; ++d) { float t = f[d] - fm; fv += t * t; }
  fv *= (1.f / 9.f);
  const float inl = 1.f / sqrtf(fv + 1e-5f);
  float fn[9];
#pragma unroll
  for (int d = 0; d < 9; ++d) fn[d] = (f[d] - fm) * inl * ln_w[d] + ln_b[d];

  if (tid == 0) {
#pragma unroll
    for (int d = 0; d < 9; ++d) red[d] = fn[d];
  }
  if (wid == 0) {
    float h = b1[lane];
#pragma unroll
    for (int d = 0; d < 9; ++d) h = fmaf(fn[d], w1[d * 64 + lane], h);
    h = fmaxf(h, 0.f);
    float l0 = h * w2[lane * 3 + 0];
    float l1 = h * w2[lane * 3 + 1];
    float l2 = h * w2[lane * 3 + 2];
#pragma unroll
    for (int d = 32; d >= 1; d >>= 1) {
      l0 += __shfl_down(l0, d, 64);
      l1 += __shfl_down(l1, d, 64);
      l2 += __shfl_down(l2, d, 64);
    }
    if (lane == 0) {
      l0 += b2[0]; l1 += b2[1]; l2 += b2[2];
      float mx = fmaxf(l0, fmaxf(l1, l2));
      float e0 = __expf(l0 - mx), e1 = __expf(l1 - mx), e2 = __expf(l2 - mx);
      float is = 1.f / (e0 + e1 + e2);
      float* o = out + (size_t)row * 3;
      o[0] = e0 * is; o[1] = e1 * is; o[2] = e2 * is;
    }
  }
  __syncthreads();
  if (tid < 9) out[(size_t)B * 3 + (size_t)row * 9 + tid] = red[tid];
}

extern "C" void kernel_launch(void* const* d_in, const int* in_sizes, int n_in,
                              void* d_out, int out_size, void* d_ws, size_t ws_size,
                              hipStream_t stream) {
  (void)n_in; (void)out_size; (void)d_ws; (void)ws_size;
  const float* x    = (const float*)d_in[0];
  const float* ln_w = (const float*)d_in[1];
  const float* ln_b = (const float*)d_in[2];
  const float* w1   = (const float*)d_in[3];
  const float* b1   = (const float*)d_in[4];
  const float* w2   = (const float*)d_in[5];
  const float* b2   = (const float*)d_in[6];
  float* out = (float*)d_out;
  const int B = in_sizes[0] / 1024;
  sr_kernel<<<B, 256, 0, stream>>>(x, ln_w, ln_b, w1, b1, w2, b2, out, B);
}

// Round 3
// 361.965 us; speedup vs baseline: 1.1801x; 1.1801x over previous
//
#include <hip/hip_runtime.h>
#include <math.h>

#define EPSF 1e-8f

__device__ __forceinline__ int PADi(int i) { return i + (i >> 5); }

template<int NV>
__device__ __forceinline__ void block_sum_batch(float* vals, float* red, int tid) {
  const int lane = tid & 63, wid = tid >> 6;
#pragma unroll
  for (int i = 0; i < NV; ++i) {
    float v = vals[i];
#pragma unroll
    for (int d = 32; d >= 1; d >>= 1) v += __shfl_down(v, d, 64);
    if (lane == 0) red[wid * NV + i] = v;
  }
  __syncthreads();
#pragma unroll
  for (int i = 0; i < NV; ++i)
    vals[i] = red[i] + red[NV + i] + red[2 * NV + i] + red[3 * NV + i];
  __syncthreads();
}

// block-wide exclusive prefix of per-thread chunk sums
__device__ __forceinline__ float block_scan_excl(float cs, float* red, int tid) {
  const int lane = tid & 63, wid = tid >> 6;
  float s = cs;
#pragma unroll
  for (int d = 1; d < 64; d <<= 1) {
    float t = __shfl_up(s, d, 64);
    if (lane >= d) s += t;
  }
  if (lane == 63) red[wid] = s;
  __syncthreads();
  float woff = 0.f;
#pragma unroll
  for (int w = 0; w < 4; ++w) woff += (w < wid) ? red[w] : 0.f;
  __syncthreads();
  return woff + s - cs;
}

// In-place radix-4 DIF stage; output digit-reversed (never reordered).
// tid->(g,j) chosen so a wave's 64 addresses spread <=2 lanes/bank with the
// i+(i>>5) pad (2-way is free on CDNA4): g = tid & (G-1), j = tid >> log2(G).
template<int LEN>
__device__ __forceinline__ void fft_stage(float* fr, float* fi, int tid) {
  constexpr int H = LEN >> 2;
  constexpr int G = 1024 / LEN;
  const int g = tid & (G - 1);
  const int j = tid / G;
  const int base = g * LEN + j;
  const int i0 = PADi(base), i1 = PADi(base + H), i2 = PADi(base + 2 * H), i3 = PADi(base + 3 * H);
  float a0r = fr[i0], a0i = fi[i0];
  float a1r = fr[i1], a1i = fi[i1];
  float a2r = fr[i2], a2i = fi[i2];
  float a3r = fr[i3], a3i = fi[i3];
  float t0r = a0r + a2r, t0i = a0i + a2i;
  float t1r = a0r - a2r, t1i = a0i - a2i;
  float t2r = a1r + a3r, t2i = a1i + a3i;
  float t3r = a1r - a3r, t3i = a1i - a3i;
  float y0r = t0r + t2r, y0i = t0i + t2i;
  float y1r = t1r + t3i, y1i = t1i - t3r;   // (t1 - i*t3)
  float y2r = t0r - t2r, y2i = t0i - t2i;
  float y3r = t1r - t3i, y3i = t1i + t3r;   // (t1 + i*t3)
  fr[i0] = y0r; fi[i0] = y0i;
  if constexpr (LEN == 4) {
    // identity twiddles on the last stage
    fr[i1] = y1r; fi[i1] = y1i;
    fr[i2] = y2r; fi[i2] = y2i;
    fr[i3] = y3r; fi[i3] = y3i;
  } else {
    constexpr float W = -6.283185307179586f * (float)(1024 / LEN) * (1.f / 1024.f);
    const float a1 = W * (float)j;
    const float a2 = a1 + a1;
    const float a3 = a2 + a1;
    const float c1 = __cosf(a1), s1 = __sinf(a1);
    const float c2 = __cosf(a2), s2 = __sinf(a2);
    const float c3 = __cosf(a3), s3 = __sinf(a3);
    fr[i1] = y1r * c1 - y1i * s1;  fi[i1] = y1r * s1 + y1i * c1;
    fr[i2] = y2r * c2 - y2i * s2;  fi[i2] = y2r * s2 + y2i * c2;
    fr[i3] = y3r * c3 - y3i * s3;  fi[i3] = y3r * s3 + y3i * c3;
  }
}

// launch_bounds note: (256,8) forced a 64-VGPR cap -> massive scratch spill
// (FETCH 66MB->700MB, WRITE 3MB->1.3GB). (256,4) caps at 128 VGPR: non-binding,
// compiler lands ~52-64 VGPR which still allows 8 waves/SIMD.
__global__ void __launch_bounds__(256, 4)
sr_kernel(const float* __restrict__ x,
          const float* __restrict__ ln_w, const float* __restrict__ ln_b,
          const float* __restrict__ w1, const float* __restrict__ b1,
          const float* __restrict__ w2, const float* __restrict__ b2,
          float* __restrict__ out, int B)
{
  __shared__ float fr[1056], fi[1056];
  __shared__ float ps[1057];          // padded prefix array: PADi indexing
  __shared__ float red[64];

  const int tid  = threadIdx.x;
  const int lane = tid & 63;
  const int wid  = tid >> 6;
  const int row  = blockIdx.x;
  if (row >= B) return;
  const float* __restrict__ xr = x + (size_t)row * 1024;

  // ---- load row ----
  const int c0 = tid * 4;
  const float4 v4 = *reinterpret_cast<const float4*>(xr + c0);
  fr[PADi(c0 + 0)] = v4.x; fr[PADi(c0 + 1)] = v4.y;
  fr[PADi(c0 + 2)] = v4.z; fr[PADi(c0 + 3)] = v4.w;
  fi[PADi(c0 + 0)] = 0.f; fi[PADi(c0 + 1)] = 0.f;
  fi[PADi(c0 + 2)] = 0.f; fi[PADi(c0 + 3)] = 0.f;
  __syncthreads();

  // ---- prefix sum of x -> ps (padded) ----
  const float cs4 = v4.x + v4.y + v4.z + v4.w;
  const float excl = block_scan_excl(cs4, red, tid);
  ps[PADi(c0 + 1)] = excl + v4.x;
  ps[PADi(c0 + 2)] = excl + v4.x + v4.y;
  ps[PADi(c0 + 3)] = excl + v4.x + v4.y + v4.z;
  ps[PADi(c0 + 4)] = excl + cs4;
  if (tid == 0) ps[0] = 0.f;

  // ---- per-thread stats from registers/LDS (x pristine in fr) ----
  const float x0 = fr[PADi(0)];
  const float xl = fr[PADi(1023)];
  float vv[14];
  vv[0] = v4.x; vv[1] = v4.y; vv[2] = v4.z; vv[3] = v4.w;
#pragma unroll
  for (int j = 4; j < 14; ++j) {
    int idx = c0 + j;
    vv[j] = (idx < 1024) ? fr[PADi(idx)] : 0.f;
  }
  float vals[16];
  vals[0] = vv[0]*vv[0] + vv[1]*vv[1] + vv[2]*vv[2] + vv[3]*vv[3];  // sum x^2
  vals[1] = vv[0] - vv[1] + vv[2] - vv[3];                           // sum (-1)^n x -> X[512]
#pragma unroll
  for (int k = 1; k <= 10; ++k) {
    float r = 0.f;
#pragma unroll
    for (int j = 0; j < 4; ++j) r += vv[j] * vv[j + k];
    vals[1 + k] = r;                                                 // raw lag product R_k
  }
  __syncthreads();   // ps fully written

  // ---- trend / kpss partials (from prefix sums only) ----
  float trv[4], str = 0.f, str2 = 0.f;
#pragma unroll
  for (int j = 0; j < 4; ++j) {
    int i = c0 + j;
    int a = i - 12; a = a < 0 ? 0 : a;
    int b = i + 12; b = b > 1023 ? 1023 : b;
    float s = ps[PADi(b + 1)] - ps[PADi(a)];
    if (i < 12)   s += (float)(12 - i) * x0;
    if (i > 1011) s += (float)(i - 1011) * xl;
    float t = s * (1.f / 25.f);
    trv[j] = t; str += t; str2 += t * t;
  }
  const float texcl = block_scan_excl(trv[0] + trv[1] + trv[2] + trv[3], red, tid);
  float run = texcl, sc = 0.f, sc2 = 0.f;
#pragma unroll
  for (int j = 0; j < 4; ++j) {
    run += trv[j];
    float c = ps[PADi(c0 + j + 1)] - run;   // cumsum(resid)[i]
    sc += c; sc2 += c * c;
  }
  vals[12] = str; vals[13] = str2; vals[14] = sc; vals[15] = sc2;
  block_sum_batch<16>(vals, red, tid);
  const float SUMSQ = vals[0];
  const float ALT   = vals[1];
  const float SUMX  = ps[PADi(1024)];

  // ---- FFT (radix-4 DIF, in place, order-free) ----
  fft_stage<1024>(fr, fi, tid); __syncthreads();
  fft_stage<256>(fr, fi, tid);  __syncthreads();
  fft_stage<64>(fr, fi, tid);   __syncthreads();
  fft_stage<16>(fr, fi, tid);   __syncthreads();
  fft_stage<4>(fr, fi, tid);    __syncthreads();

  // ---- psd reductions over full spectrum ----
  float pq[4], psum = 0.f, pmax = 0.f;
#pragma unroll
  for (int q = 0; q < 4; ++q) {
    int p = tid + q * 256;
    float rr = fr[PADi(p)], ii = fi[PADi(p)];
    float pp = fmaxf(rr * rr + ii * ii, EPSF);
    pq[q] = pp; psum += pp; pmax = fmaxf(pmax, pp);
  }
#pragma unroll
  for (int d = 32; d >= 1; d >>= 1) {
    psum += __shfl_down(psum, d, 64);
    pmax = fmaxf(pmax, __shfl_down(pmax, d, 64));
  }
  if (lane == 0) { red[wid] = psum; red[4 + wid] = pmax; }
  __syncthreads();
  const float SFULL = red[0] + red[1] + red[2] + red[3];
  const float PMAX  = fmaxf(fmaxf(red[4], red[5]), fmaxf(red[6], red[7]));
  __syncthreads();
  const float p0b   = fmaxf(SUMX * SUMX, EPSF);   // |X[0]|^2 exactly
  const float p512b = fmaxf(ALT * ALT, EPSF);     // |X[512]|^2 exactly
  const float Sr    = 0.5f * (SFULL + p0b + p512b);   // rfft psd sum
  const float invS  = 1.f / Sr;
  float ts[1]; ts[0] = 0.f;
#pragma unroll
  for (int q = 0; q < 4; ++q) {
    float pn = pq[q] * invS;
    ts[0] += pn * __logf(pn + EPSF);
  }
  block_sum_batch<1>(ts, red, tid);
  const float g0   = (p0b * invS)   * __logf(p0b * invS + EPSF);
  const float g512 = (p512b * invS) * __logf(p512b * invS + EPSF);
  const float ent  = -0.5f * (ts[0] + g0 + g512);

  // ---- features ----
  const float m = SUMX * (1.f / 1024.f);
  const float den = SUMSQ - 1024.f * m * m + EPSF;
  const float invden = 1.f / den;
  float acf1 = 0.f, acf2 = 0.f, lbq = 0.f;
#pragma unroll
  for (int k = 1; k <= 10; ++k) {
    float num = vals[1 + k]
              - m * (ps[PADi(1024 - k)] + (SUMX - ps[PADi(k)]))
              + (float)(1024 - k) * m * m;
    float a = fminf(fmaxf(num * invden, -1.f), 1.f);
    if (k == 1) acf1 = a;
    else if (k == 2) acf2 = a;
    lbq += a * a;
  }
  const float spent = fminf(fmaxf(ent / (__logf(513.f + EPSF) + EPSF), 0.f), 1.f);
  const float peak  = fminf(fmaxf(PMAX / (Sr + EPSF), 0.f), 1.f);
  const float R1 = vals[2];
  const float phi = fminf(fmaxf(R1 / ((SUMSQ - xl * xl) + EPSF), -1.f), 1.f);
  const float invn = 1.f / 1023.f;
  const float sum_d2 = 2.f * SUMSQ - x0 * x0 - xl * xl - 2.f * R1;
  const float md = (xl - x0) * invn;
  const float diff_var = sum_d2 * invn - md * md;
  const float STR = vals[12], STR2 = vals[13], SC = vals[14], SC2 = vals[15];
  const float tstr = STR2 * (1.f / 1024.f) - (STR * (1.f / 1024.f)) * (STR * (1.f / 1024.f));
  const float varx = SUMSQ * (1.f / 1024.f) - m * m;
  const float mc = SC * (1.f / 1024.f);
  const float kpss = (SC2 * (1.f / 1024.f) - mc * mc) / (varx + 1e-8f);

  float f[9] = {acf1, acf2, spent, phi, diff_var, tstr, kpss, lbq, peak};
  float fm = 0.f;
#pragma unroll
  for (int d = 0; d < 9; ++d) fm += f[d];
  fm *= (1.f / 9.f);
  float fv = 0.f;
#pragma unroll
  for (int d = 0; d < 9; ++d) { float t = f[d] - fm; fv += t * t; }
  fv *= (1.f / 9.f);
  const float inl = 1.f / sqrtf(fv + 1e-5f);
  float fn[9];
#pragma unroll
  for (int d = 0; d < 9; ++d) fn[d] = (f[d] - fm) * inl * ln_w[d] + ln_b[d];

  if (tid == 0) {
#pragma unroll
    for (int d = 0; d < 9; ++d) red[d] = fn[d];
  }
  if (wid == 0) {
    float h = b1[lane];
#pragma unroll
    for (int d = 0; d < 9; ++d) h = fmaf(fn[d], w1[d * 64 + lane], h);
    h = fmaxf(h, 0.f);
    float l0 = h * w2[lane * 3 + 0];
    float l1 = h * w2[lane * 3 + 1];
    float l2 = h * w2[lane * 3 + 2];
#pragma unroll
    for (int d = 32; d >= 1; d >>= 1) {
      l0 += __shfl_down(l0, d, 64);
      l1 += __shfl_down(l1, d, 64);
      l2 += __shfl_down(l2, d, 64);
    }
    if (lane == 0) {
      l0 += b2[0]; l1 += b2[1]; l2 += b2[2];
      float mx = fmaxf(l0, fmaxf(l1, l2));
      float e0 = __expf(l0 - mx), e1 = __expf(l1 - mx), e2 = __expf(l2 - mx);
      float is = 1.f / (e0 + e1 + e2);
      float* o = out + (size_t)row * 3;
      o[0] = e0 * is; o[1] = e1 * is; o[2] = e2 * is;
    }
  }
  __syncthreads();
  if (tid < 9) out[(size_t)B * 3 + (size_t)row * 9 + tid] = red[tid];
}

extern "C" void kernel_launch(void* const* d_in, const int* in_sizes, int n_in,
                              void* d_out, int out_size, void* d_ws, size_t ws_size,
                              hipStream_t stream) {
  (void)n_in; (void)out_size; (void)d_ws; (void)ws_size;
  const float* x    = (const float*)d_in[0];
  const float* ln_w = (const float*)d_in[1];
  const float* ln_b = (const float*)d_in[2];
  const float* w1   = (const float*)d_in[3];
  const float* b1   = (const float*)d_in[4];
  const float* w2   = (const float*)d_in[5];
  const float* b2   = (const float*)d_in[6];
  float* out = (float*)d_out;
  const int B = in_sizes[0] / 1024;
  sr_kernel<<<B, 256, 0, stream>>>(x, ln_w, ln_b, w1, b1, w2, b2, out, B);
}

// Round 4
// 171.805 us; speedup vs baseline: 2.4863x; 2.1068x over previous
//
#include <hip/hip_runtime.h>
#include <math.h>

#define EPSF 1e-8f

__device__ __forceinline__ float bcf(int x){ return __builtin_bit_cast(float, x); }
__device__ __forceinline__ int   bci(float x){ return __builtin_bit_cast(int, x); }

// DPP move with old=0: lanes not updated (row_mask / OOB with bound_ctrl=false) yield 0.
template<int CTRL, int RM>
__device__ __forceinline__ float dpp0(float v){
  return bcf(__builtin_amdgcn_update_dpp(0, bci(v), CTRL, RM, 0xF, false));
}

// Inclusive 64-lane scan, VALU-only (row_shr 1,2,4,8 then row_bcast15->rows{1,3}, bcast31->rows{2,3})
__device__ __forceinline__ float wave_iscan_add(float v){
  v += dpp0<0x111,0xF>(v);
  v += dpp0<0x112,0xF>(v);
  v += dpp0<0x114,0xF>(v);
  v += dpp0<0x118,0xF>(v);
  v += dpp0<0x142,0xA>(v);
  v += dpp0<0x143,0xC>(v);
  return v;
}
__device__ __forceinline__ float wave_red_add(float v){ return wave_iscan_add(v); } // lane63 = total
__device__ __forceinline__ float wave_red_max_pos(float v){ // valid for v >= 0 (filler is 0)
  v = fmaxf(v, dpp0<0x111,0xF>(v));
  v = fmaxf(v, dpp0<0x112,0xF>(v));
  v = fmaxf(v, dpp0<0x114,0xF>(v));
  v = fmaxf(v, dpp0<0x118,0xF>(v));
  v = fmaxf(v, dpp0<0x142,0xA>(v));
  v = fmaxf(v, dpp0<0x143,0xC>(v));
  return v;
}
__device__ __forceinline__ float readlane_f(float v, int l){
  return bcf(__builtin_amdgcn_readlane(bci(v), l));
}

// interleaved-complex LDS index with pad every 16 complex (conflict-free in all stages)
__device__ __forceinline__ int FI(int i){ return i + (i >> 4); }

// In-place radix-4 DIF stage on interleaved complex; output digit-reversed (never reordered).
template<int LEN>
__device__ __forceinline__ void fft_stage(float2* fc, int tid){
  constexpr int H = LEN >> 2;
  constexpr int G = 1024 / LEN;
  const int g = tid & (G - 1);
  const int j = tid / G;
  const int base = g * LEN + j;
  float2 a0 = fc[FI(base)];
  float2 a1 = fc[FI(base + H)];
  float2 a2 = fc[FI(base + 2*H)];
  float2 a3 = fc[FI(base + 3*H)];
  float t0r = a0.x + a2.x, t0i = a0.y + a2.y;
  float t1r = a0.x - a2.x, t1i = a0.y - a2.y;
  float t2r = a1.x + a3.x, t2i = a1.y + a3.y;
  float t3r = a1.x - a3.x, t3i = a1.y - a3.y;
  float y0r = t0r + t2r, y0i = t0i + t2i;
  float y1r = t1r + t3i, y1i = t1i - t3r;
  float y2r = t0r - t2r, y2i = t0i - t2i;
  float y3r = t1r - t3i, y3i = t1i + t3r;
  fc[FI(base)] = make_float2(y0r, y0i);
  constexpr float W = -6.283185307179586f / (float)LEN;
  const float a1a = W * (float)j;
  const float a2a = a1a + a1a;
  const float a3a = a2a + a1a;
  const float c1 = __cosf(a1a), s1 = __sinf(a1a);
  const float c2 = __cosf(a2a), s2 = __sinf(a2a);
  const float c3 = __cosf(a3a), s3 = __sinf(a3a);
  fc[FI(base + H)]   = make_float2(y1r*c1 - y1i*s1, y1r*s1 + y1i*c1);
  fc[FI(base + 2*H)] = make_float2(y2r*c2 - y2i*s2, y2r*s2 + y2i*c2);
  fc[FI(base + 3*H)] = make_float2(y3r*c3 - y3i*s3, y3r*s3 + y3i*c3);
}

__global__ void __launch_bounds__(256)
sr_kernel(const float* __restrict__ x,
          const float* __restrict__ ln_w, const float* __restrict__ ln_b,
          const float* __restrict__ w1, const float* __restrict__ b1,
          const float* __restrict__ w2, const float* __restrict__ b2,
          float* __restrict__ out, int B)
{
  __shared__ __align__(16) float2 fc[1088];       // 1024 complex + pad16
  __shared__ __align__(16) float Sg[1056];        // S = Sg+16; guards: S[-16..-1]=0, S[1024..1039]=SUMX
  __shared__ __align__(16) float red[96];
  // red layout (value v at red[4v+wid]): v0 SUMSQ, v1..10 R1..R10, v11 STR, v12 STR2,
  // v13 SC, v14 SC2, v15 TS; [64..67] ALT, [68..71] psum, [72..75] pmax, [76..79] ws, [80..83] tws

  const int tid  = threadIdx.x;
  const int lane = tid & 63;
  const int wid  = tid >> 6;
  const int row  = blockIdx.x;
  const float* __restrict__ xr = x + (size_t)row * 1024;
  float* S = Sg + 16;

  const int c0 = tid * 4;
  const float4 v4 = *reinterpret_cast<const float4*>(xr + c0);
  float vx[16];
  vx[0]=v4.x; vx[1]=v4.y; vx[2]=v4.z; vx[3]=v4.w;
  if (tid < 253) {   // c0+15 <= 1023: vector reload (L1-hit, vm pipe — not ds pipe)
    const float4 n1 = *reinterpret_cast<const float4*>(xr + c0 + 4);
    const float4 n2 = *reinterpret_cast<const float4*>(xr + c0 + 8);
    const float4 n3 = *reinterpret_cast<const float4*>(xr + c0 + 12);
    vx[4]=n1.x; vx[5]=n1.y; vx[6]=n1.z; vx[7]=n1.w;
    vx[8]=n2.x; vx[9]=n2.y; vx[10]=n2.z; vx[11]=n2.w;
    vx[12]=n3.x; vx[13]=n3.y; vx[14]=n3.z; vx[15]=n3.w;
  } else {
#pragma unroll
    for (int jj = 4; jj < 16; ++jj) {
      int idx = c0 + jj;
      vx[jj] = (idx < 1024) ? xr[idx] : 0.f;
    }
  }
  const float x0 = xr[0];
  const float xl = xr[1023];

  // ---- stage x into fc ----
#pragma unroll
  for (int jj = 0; jj < 4; ++jj) fc[FI(c0 + jj)] = make_float2(vx[jj], 0.f);

  // ---- per-thread partials ----
  float sumsq = vx[0]*vx[0] + vx[1]*vx[1] + vx[2]*vx[2] + vx[3]*vx[3];
  float alt   = vx[0] - vx[1] + vx[2] - vx[3];
  float Rp[10];
#pragma unroll
  for (int k = 1; k <= 10; ++k) {
    float r = 0.f;
#pragma unroll
    for (int jj = 0; jj < 4; ++jj) r += vx[jj] * vx[jj + k];
    Rp[k-1] = r;
  }
  {
    float r;
    r = wave_red_add(sumsq); if (lane == 63) red[0*4 + wid] = r;
#pragma unroll
    for (int k = 0; k < 10; ++k) { r = wave_red_add(Rp[k]); if (lane == 63) red[(1+k)*4 + wid] = r; }
    r = wave_red_add(alt);   if (lane == 63) red[64 + wid] = r;
  }
  const float cs4 = vx[0] + vx[1] + vx[2] + vx[3];
  const float incl = wave_iscan_add(cs4);
  if (lane == 63) red[76 + wid] = incl;
  __syncthreads();                                   // B1

  // ---- prefix S + guards ----
  const float4 wsv = *reinterpret_cast<const float4*>(&red[76]);
  const float SUMX = wsv.x + wsv.y + wsv.z + wsv.w;
  float woff = 0.f;
  if (wid > 0) woff += wsv.x;
  if (wid > 1) woff += wsv.y;
  if (wid > 2) woff += wsv.z;
  const float excl = woff + incl - cs4;
  const float s0 = excl + vx[0], s1 = s0 + vx[1], s2 = s1 + vx[2], s3 = s2 + vx[3];
  *reinterpret_cast<float4*>(&S[c0]) = make_float4(s0, s1, s2, s3);
  if (tid < 16) { Sg[tid] = 0.f; S[1024 + tid] = SUMX; }
  __syncthreads();                                   // B2

  // ---- trend (window +-12 via S; guards absorb clamps) ----
  const float4 Ar = *reinterpret_cast<const float4*>(&S[c0 - 16]);
  const float4 Br = *reinterpret_cast<const float4*>(&S[c0 - 12]);
  const float4 Cr = *reinterpret_cast<const float4*>(&S[c0 + 12]);
  const float slo[4] = {Ar.w, Br.x, Br.y, Br.z};   // S[i-13]
  const float shi[4] = {Cr.x, Cr.y, Cr.z, Cr.w};   // S[i+12]
  float trv[4], str = 0.f, str2 = 0.f;
#pragma unroll
  for (int jj = 0; jj < 4; ++jj) {
    int i = c0 + jj;
    float s = shi[jj] - slo[jj];
    if (i < 12)   s += (float)(12 - i) * x0;
    if (i > 1011) s += (float)(i - 1011) * xl;
    float t = s * (1.f / 25.f);
    trv[jj] = t; str += t; str2 += t * t;
  }
  const float tsum = trv[0] + trv[1] + trv[2] + trv[3];
  const float tincl = wave_iscan_add(tsum);
  if (lane == 63) red[80 + wid] = tincl;
  {
    float r;
    r = wave_red_add(str);  if (lane == 63) red[11*4 + wid] = r;
    r = wave_red_add(str2); if (lane == 63) red[12*4 + wid] = r;
  }
  __syncthreads();                                   // B3

  {
    const float4 twsv = *reinterpret_cast<const float4*>(&red[80]);
    float twoff = 0.f;
    if (wid > 0) twoff += twsv.x;
    if (wid > 1) twoff += twsv.y;
    if (wid > 2) twoff += twsv.z;
    float runv = twoff + tincl - tsum;
    const float sarr[4] = {s0, s1, s2, s3};
    float sc = 0.f, sc2 = 0.f;
#pragma unroll
    for (int jj = 0; jj < 4; ++jj) {
      runv += trv[jj];
      float c = sarr[jj] - runv;                     // cumsum(resid)[i]
      sc += c; sc2 += c * c;
    }
    float r;
    r = wave_red_add(sc);  if (lane == 63) red[13*4 + wid] = r;
    r = wave_red_add(sc2); if (lane == 63) red[14*4 + wid] = r;
  }

  // ---- FFT (stages 1-4 in LDS; stage 5 fused into psd) ----
  fft_stage<1024>(fc, tid); __syncthreads();         // B4
  fft_stage<256>(fc, tid);  __syncthreads();         // B5
  fft_stage<64>(fc, tid);   __syncthreads();         // B6
  fft_stage<16>(fc, tid);   __syncthreads();         // B7

  // final stage (identity twiddles) fused with psd — psd reductions are
  // permutation-invariant over the full spectrum, outputs never touch LDS
  float pq[4], psum = 0.f, pmax = 0.f;
  {
    const int base = 4 * tid;
    float2 a0 = fc[FI(base)], a1 = fc[FI(base+1)], a2 = fc[FI(base+2)], a3 = fc[FI(base+3)];
    float t0r = a0.x + a2.x, t0i = a0.y + a2.y;
    float t1r = a0.x - a2.x, t1i = a0.y - a2.y;
    float t2r = a1.x + a3.x, t2i = a1.y + a3.y;
    float t3r = a1.x - a3.x, t3i = a1.y - a3.y;
    float y0r = t0r + t2r, y0i = t0i + t2i;
    float y1r = t1r + t3i, y1i = t1i - t3r;
    float y2r = t0r - t2r, y2i = t0i - t2i;
    float y3r = t1r - t3i, y3i = t1i + t3r;
    pq[0] = fmaxf(y0r*y0r + y0i*y0i, EPSF);
    pq[1] = fmaxf(y1r*y1r + y1i*y1i, EPSF);
    pq[2] = fmaxf(y2r*y2r + y2i*y2i, EPSF);
    pq[3] = fmaxf(y3r*y3r + y3i*y3i, EPSF);
#pragma unroll
    for (int q = 0; q < 4; ++q) { psum += pq[q]; pmax = fmaxf(pmax, pq[q]); }
  }
  {
    float r;
    r = wave_red_add(psum);     if (lane == 63) red[68 + wid] = r;
    r = wave_red_max_pos(pmax); if (lane == 63) red[72 + wid] = r;
  }
  __syncthreads();                                   // B8

  const float4 pssv = *reinterpret_cast<const float4*>(&red[68]);
  const float SFULL = pssv.x + pssv.y + pssv.z + pssv.w;
  const float4 pmv = *reinterpret_cast<const float4*>(&red[72]);
  const float PMAX = fmaxf(fmaxf(pmv.x, pmv.y), fmaxf(pmv.z, pmv.w));
  const float4 altv = *reinterpret_cast<const float4*>(&red[64]);
  const float ALT = altv.x + altv.y + altv.z + altv.w;
  const float p0b   = fmaxf(SUMX * SUMX, EPSF);
  const float p512b = fmaxf(ALT * ALT, EPSF);
  const float Sr    = 0.5f * (SFULL + p0b + p512b);
  const float invS  = 1.f / Sr;
  float ts = 0.f;
#pragma unroll
  for (int q = 0; q < 4; ++q) { float pn = pq[q] * invS; ts += pn * __logf(pn + EPSF); }
  { float r = wave_red_add(ts); if (lane == 63) red[15*4 + wid] = r; }
  __syncthreads();                                   // B9

  // ---- wave 0: gather sums, features, LN, MLP, stores ----
  if (wid == 0) {
    float vsum;
    {
      const float4 q4 = *reinterpret_cast<const float4*>(&red[(lane & 15) * 4]);
      vsum = q4.x + q4.y + q4.z + q4.w;
    }
    const float SUMSQ = readlane_f(vsum, 0);
    float Rk[10];
#pragma unroll
    for (int k = 0; k < 10; ++k) Rk[k] = readlane_f(vsum, 1 + k);
    const float STR  = readlane_f(vsum, 11);
    const float STR2 = readlane_f(vsum, 12);
    const float SC   = readlane_f(vsum, 13);
    const float SC2  = readlane_f(vsum, 14);
    const float TS   = readlane_f(vsum, 15);

    const float m = SUMX * (1.f / 1024.f);
    const float den = SUMSQ - 1024.f * m * m + EPSF;
    const float invden = 1.f / den;
    const float4 sa  = *reinterpret_cast<const float4*>(&S[0]);
    const float4 sb  = *reinterpret_cast<const float4*>(&S[4]);
    const float4 sg2 = *reinterpret_cast<const float4*>(&S[8]);
    const float4 sd  = *reinterpret_cast<const float4*>(&S[1012]);
    const float4 se  = *reinterpret_cast<const float4*>(&S[1016]);
    const float4 sf  = *reinterpret_cast<const float4*>(&S[1020]);
    const float Slo[10] = {sa.x,sa.y,sa.z,sa.w, sb.x,sb.y,sb.z,sb.w, sg2.x,sg2.y}; // S[k-1]
    const float Shi[10] = {sf.z,sf.y,sf.x,se.w, se.z,se.y,se.x,sd.w, sd.z,sd.y};   // S[1023-k]
    float acf1 = 0.f, acf2 = 0.f, lbq = 0.f;
#pragma unroll
    for (int k = 1; k <= 10; ++k) {
      float num = Rk[k-1] - m * (Shi[k-1] + (SUMX - Slo[k-1])) + (float)(1024 - k) * m * m;
      float a = fminf(fmaxf(num * invden, -1.f), 1.f);
      if (k == 1) acf1 = a;
      else if (k == 2) acf2 = a;
      lbq += a * a;
    }
    const float g0   = (p0b * invS)   * __logf(p0b * invS + EPSF);
    const float g512 = (p512b * invS) * __logf(p512b * invS + EPSF);
    const float ent  = -0.5f * (TS + g0 + g512);
    const float spent = fminf(fmaxf(ent / (__logf(513.f + EPSF) + EPSF), 0.f), 1.f);
    const float peak  = fminf(fmaxf(PMAX / (Sr + EPSF), 0.f), 1.f);
    const float R1v = Rk[0];
    const float phi = fminf(fmaxf(R1v / ((SUMSQ - xl * xl) + EPSF), -1.f), 1.f);
    const float invn = 1.f / 1023.f;
    const float sum_d2 = 2.f * SUMSQ - x0 * x0 - xl * xl - 2.f * R1v;
    const float md = (xl - x0) * invn;
    const float diff_var = sum_d2 * invn - md * md;
    const float tstr = STR2 * (1.f / 1024.f) - (STR * (1.f / 1024.f)) * (STR * (1.f / 1024.f));
    const float varx = SUMSQ * (1.f / 1024.f) - m * m;
    const float mc = SC * (1.f / 1024.f);
    const float kpss = (SC2 * (1.f / 1024.f) - mc * mc) / (varx + 1e-8f);

    float f[9] = {acf1, acf2, spent, phi, diff_var, tstr, kpss, lbq, peak};
    float fm = 0.f;
#pragma unroll
    for (int d = 0; d < 9; ++d) fm += f[d];
    fm *= (1.f / 9.f);
    float fv = 0.f;
#pragma unroll
    for (int d = 0; d < 9; ++d) { float t = f[d] - fm; fv += t * t; }
    fv *= (1.f / 9.f);
    const float inl = 1.f / sqrtf(fv + 1e-5f);
    float fn[9];
#pragma unroll
    for (int d = 0; d < 9; ++d) fn[d] = (f[d] - fm) * inl * ln_w[d] + ln_b[d];

    float h = b1[lane];
#pragma unroll
    for (int d = 0; d < 9; ++d) h = fmaf(fn[d], w1[d * 64 + lane], h);
    h = fmaxf(h, 0.f);
    float l0 = h * w2[lane * 3 + 0];
    float l1 = h * w2[lane * 3 + 1];
    float l2 = h * w2[lane * 3 + 2];
    l0 = wave_red_add(l0);
    l1 = wave_red_add(l1);
    l2 = wave_red_add(l2);
    const float L0 = readlane_f(l0, 63) + b2[0];
    const float L1 = readlane_f(l1, 63) + b2[1];
    const float L2 = readlane_f(l2, 63) + b2[2];
    if (lane == 0) {
      const float mx = fmaxf(L0, fmaxf(L1, L2));
      const float e0 = __expf(L0 - mx), e1 = __expf(L1 - mx), e2 = __expf(L2 - mx);
      const float is = 1.f / (e0 + e1 + e2);
      float* o = out + (size_t)row * 3;
      o[0] = e0 * is; o[1] = e1 * is; o[2] = e2 * is;
      float* fo = out + (size_t)B * 3 + (size_t)row * 9;
      fo[0] = fn[0]; fo[1] = fn[1]; fo[2] = fn[2]; fo[3] = fn[3]; fo[4] = fn[4];
      fo[5] = fn[5]; fo[6] = fn[6]; fo[7] = fn[7]; fo[8] = fn[8];
    }
  }
}

extern "C" void kernel_launch(void* const* d_in, const int* in_sizes, int n_in,
                              void* d_out, int out_size, void* d_ws, size_t ws_size,
                              hipStream_t stream) {
  (void)n_in; (void)out_size; (void)d_ws; (void)ws_size;
  const float* x    = (const float*)d_in[0];
  const float* ln_w = (const float*)d_in[1];
  const float* ln_b = (const float*)d_in[2];
  const float* w1   = (const float*)d_in[3];
  const float* b1   = (const float*)d_in[4];
  const float* w2   = (const float*)d_in[5];
  const float* b2   = (const float*)d_in[6];
  float* out = (float*)d_out;
  const int B = in_sizes[0] / 1024;
  sr_kernel<<<B, 256, 0, stream>>>(x, ln_w, ln_b, w1, b1, w2, b2, out, B);
}

// Round 5
// 162.371 us; speedup vs baseline: 2.6307x; 1.0581x over previous
//
#include <hip/hip_runtime.h>
#include <math.h>

#define EPSF 1e-8f

__device__ __forceinline__ float bcf(int x){ return __builtin_bit_cast(float, x); }
__device__ __forceinline__ int   bci(float x){ return __builtin_bit_cast(int, x); }

// DPP move with old=0: lanes not updated yield 0.
template<int CTRL, int RM>
__device__ __forceinline__ float dpp0(float v){
  return bcf(__builtin_amdgcn_update_dpp(0, bci(v), CTRL, RM, 0xF, false));
}

__device__ __forceinline__ float wave_iscan_add(float v){
  v += dpp0<0x111,0xF>(v);
  v += dpp0<0x112,0xF>(v);
  v += dpp0<0x114,0xF>(v);
  v += dpp0<0x118,0xF>(v);
  v += dpp0<0x142,0xA>(v);
  v += dpp0<0x143,0xC>(v);
  return v;
}
__device__ __forceinline__ float wave_red_add(float v){ return wave_iscan_add(v); } // lane63 = total
__device__ __forceinline__ float wave_red_max_pos(float v){ // valid for v >= 0
  v = fmaxf(v, dpp0<0x111,0xF>(v));
  v = fmaxf(v, dpp0<0x112,0xF>(v));
  v = fmaxf(v, dpp0<0x114,0xF>(v));
  v = fmaxf(v, dpp0<0x118,0xF>(v));
  v = fmaxf(v, dpp0<0x142,0xA>(v));
  v = fmaxf(v, dpp0<0x143,0xC>(v));
  return v;
}
__device__ __forceinline__ float readlane_f(float v, int l){
  return bcf(__builtin_amdgcn_readlane(bci(v), l));
}

// XOR swizzle for interleaved-complex (8B) LDS. Bijective on [0,1024).
// Per-stage rank analysis (32-lane phases, slot = FI mod 16):
// staging/fused: s={l2^l4, l3, l0^l4, l1}; 1024: {l0^l4,l1,l2,l3}; 256: {l2,l3,l4^l0,l1};
// 64: {l4^l0, l1, l0^l2, l1^l3}; 16: {l0^l2, l1^l3, l2^l4, l3} — all rank 4 -> 2 lanes/slot (min).
__device__ __forceinline__ int FI(int i){ return i ^ (((i >> 4) ^ (i >> 6)) & 15); }

// In-place radix-4 DIF stage; output digit-reversed (never reordered).
// Twiddles: 2 trans ops + double-angle/addition recurrence.
template<int LEN>
__device__ __forceinline__ void fft_stage(float2* fc, int tid){
  constexpr int H = LEN >> 2;
  constexpr int G = 1024 / LEN;
  const int g = tid & (G - 1);
  const int j = tid / G;
  const int base = g * LEN + j;
  const int i0 = FI(base), i1 = FI(base + H), i2 = FI(base + 2*H), i3 = FI(base + 3*H);
  float2 a0 = fc[i0];
  float2 a1 = fc[i1];
  float2 a2 = fc[i2];
  float2 a3 = fc[i3];
  float t0r = a0.x + a2.x, t0i = a0.y + a2.y;
  float t1r = a0.x - a2.x, t1i = a0.y - a2.y;
  float t2r = a1.x + a3.x, t2i = a1.y + a3.y;
  float t3r = a1.x - a3.x, t3i = a1.y - a3.y;
  float y0r = t0r + t2r, y0i = t0i + t2i;
  float y1r = t1r + t3i, y1i = t1i - t3r;
  float y2r = t0r - t2r, y2i = t0i - t2i;
  float y3r = t1r - t3i, y3i = t1i + t3r;
  fc[i0] = make_float2(y0r, y0i);
  constexpr float W = -6.283185307179586f / (float)LEN;
  const float a1a = W * (float)j;
  const float c1 = __cosf(a1a), s1 = __sinf(a1a);
  const float c2 = 1.f - 2.f*s1*s1, s2 = 2.f*s1*c1;     // double angle
  const float c3 = c1*c2 - s1*s2,  s3 = s1*c2 + c1*s2;  // angle addition
  fc[i1] = make_float2(y1r*c1 - y1i*s1, y1r*s1 + y1i*c1);
  fc[i2] = make_float2(y2r*c2 - y2i*s2, y2r*s2 + y2i*c2);
  fc[i3] = make_float2(y3r*c3 - y3i*s3, y3r*s3 + y3i*c3);
}

__global__ void __launch_bounds__(256)
sr_kernel(const float* __restrict__ x,
          const float* __restrict__ ln_w, const float* __restrict__ ln_b,
          const float* __restrict__ w1, const float* __restrict__ b1,
          const float* __restrict__ w2, const float* __restrict__ b2,
          float* __restrict__ out, int B)
{
  __shared__ __align__(16) float2 fc[1024];     // XOR-swizzled complex
  __shared__ __align__(16) float Sg[1056];      // S = Sg+16; guards both ends
  __shared__ __align__(16) float red[96];
  // red[4v+wid]: v0 SUMSQ, v1..10 R1..R10, v11 STR, v12 STR2, v13 SC, v14 SC2, v15 PLOG
  // [64..67] ALT, [68..71] psum, [72..75] pmax, [76..79] ws, [80..83] tws

  const int tid  = threadIdx.x;
  const int lane = tid & 63;
  const int wid  = tid >> 6;
  const int row  = blockIdx.x;
  if (row >= B) return;
  const float* __restrict__ xr = x + (size_t)row * 1024;
  float* S = Sg + 16;

  // ======== phase A: load, stage, per-thread partials, reductions ========
  const int c0 = tid * 4;
  const float4 v4 = *reinterpret_cast<const float4*>(xr + c0);
  float vx[16];
  vx[0]=v4.x; vx[1]=v4.y; vx[2]=v4.z; vx[3]=v4.w;
  if (tid < 253) {   // vector reload of neighbors (L1-hit, vm pipe)
    const float4 n1 = *reinterpret_cast<const float4*>(xr + c0 + 4);
    const float4 n2 = *reinterpret_cast<const float4*>(xr + c0 + 8);
    const float4 n3 = *reinterpret_cast<const float4*>(xr + c0 + 12);
    vx[4]=n1.x; vx[5]=n1.y; vx[6]=n1.z; vx[7]=n1.w;
    vx[8]=n2.x; vx[9]=n2.y; vx[10]=n2.z; vx[11]=n2.w;
    vx[12]=n3.x; vx[13]=n3.y; vx[14]=n3.z; vx[15]=n3.w;
  } else {
#pragma unroll
    for (int jj = 4; jj < 16; ++jj) {
      int idx = c0 + jj;
      vx[jj] = (idx < 1024) ? xr[idx] : 0.f;
    }
  }
  const float x0 = xr[0];
  const float xl = xr[1023];

#pragma unroll
  for (int jj = 0; jj < 4; ++jj) fc[FI(c0 + jj)] = make_float2(vx[jj], 0.f);

  float sumsq = vx[0]*vx[0] + vx[1]*vx[1] + vx[2]*vx[2] + vx[3]*vx[3];
  float alt   = vx[0] - vx[1] + vx[2] - vx[3];
  float Rp[10];
#pragma unroll
  for (int k = 1; k <= 10; ++k) {
    float r = 0.f;
#pragma unroll
    for (int jj = 0; jj < 4; ++jj) r += vx[jj] * vx[jj + k];
    Rp[k-1] = r;
  }
  {
    float r;
    r = wave_red_add(sumsq); if (lane == 63) red[0*4 + wid] = r;
#pragma unroll
    for (int k = 0; k < 10; ++k) { r = wave_red_add(Rp[k]); if (lane == 63) red[(1+k)*4 + wid] = r; }
    r = wave_red_add(alt);   if (lane == 63) red[64 + wid] = r;
  }
  const float cs4 = vx[0] + vx[1] + vx[2] + vx[3];
  const float incl = wave_iscan_add(cs4);
  if (lane == 63) red[76 + wid] = incl;
  __syncthreads();                                   // B1

  // ======== phase B: fft stage 1 (in-place, per-thread-disjoint) || prefix S ========
  fft_stage<1024>(fc, tid);
  const float4 wsv = *reinterpret_cast<const float4*>(&red[76]);
  const float SUMX = wsv.x + wsv.y + wsv.z + wsv.w;
  float woff = 0.f;
  if (wid > 0) woff += wsv.x;
  if (wid > 1) woff += wsv.y;
  if (wid > 2) woff += wsv.z;
  const float excl = woff + incl - cs4;
  const float s0 = excl + vx[0], s1 = s0 + vx[1], s2 = s1 + vx[2], s3 = s2 + vx[3];
  *reinterpret_cast<float4*>(&S[c0]) = make_float4(s0, s1, s2, s3);
  if (tid < 16) { Sg[tid] = 0.f; S[1024 + tid] = SUMX; }
  __syncthreads();                                   // B2

  // ======== phase C: fft stage 2 || trend from S ========
  fft_stage<256>(fc, tid);
  const float4 Ar = *reinterpret_cast<const float4*>(&S[c0 - 16]);
  const float4 Br = *reinterpret_cast<const float4*>(&S[c0 - 12]);
  const float4 Cr = *reinterpret_cast<const float4*>(&S[c0 + 12]);
  const float slo[4] = {Ar.w, Br.x, Br.y, Br.z};   // S[i-13]
  const float shi[4] = {Cr.x, Cr.y, Cr.z, Cr.w};   // S[i+12]
  float trv[4], str = 0.f, str2 = 0.f;
#pragma unroll
  for (int jj = 0; jj < 4; ++jj) {
    int i = c0 + jj;
    float s = shi[jj] - slo[jj];
    if (i < 12)   s += (float)(12 - i) * x0;
    if (i > 1011) s += (float)(i - 1011) * xl;
    float t = s * (1.f / 25.f);
    trv[jj] = t; str += t; str2 += t * t;
  }
  const float tsum = trv[0] + trv[1] + trv[2] + trv[3];
  const float tincl = wave_iscan_add(tsum);
  if (lane == 63) red[80 + wid] = tincl;
  {
    float r;
    r = wave_red_add(str);  if (lane == 63) red[11*4 + wid] = r;
    r = wave_red_add(str2); if (lane == 63) red[12*4 + wid] = r;
  }
  __syncthreads();                                   // B3

  // ======== phase D: fft stage 3 || cumsum(resid) stats ========
  fft_stage<64>(fc, tid);
  {
    const float4 twsv = *reinterpret_cast<const float4*>(&red[80]);
    float twoff = 0.f;
    if (wid > 0) twoff += twsv.x;
    if (wid > 1) twoff += twsv.y;
    if (wid > 2) twoff += twsv.z;
    float runv = twoff + tincl - tsum;
    const float sarr[4] = {s0, s1, s2, s3};
    float sc = 0.f, sc2 = 0.f;
#pragma unroll
    for (int jj = 0; jj < 4; ++jj) {
      runv += trv[jj];
      float c = sarr[jj] - runv;                     // cumsum(resid)[i]
      sc += c; sc2 += c * c;
    }
    float r;
    r = wave_red_add(sc);  if (lane == 63) red[13*4 + wid] = r;
    r = wave_red_add(sc2); if (lane == 63) red[14*4 + wid] = r;
  }
  __syncthreads();                                   // B4

  // ======== phase E: fft stage 4 ========
  fft_stage<16>(fc, tid);
  __syncthreads();                                   // B5

  // ======== phase F: fused final stage + psd (sum, max, sum p*log p) ========
  float psum = 0.f, pmax = 0.f, plog = 0.f;
  {
    const int b4 = 4 * tid;
    float2 a0 = fc[FI(b4)], a1 = fc[FI(b4+1)], a2 = fc[FI(b4+2)], a3 = fc[FI(b4+3)];
    float t0r = a0.x + a2.x, t0i = a0.y + a2.y;
    float t1r = a0.x - a2.x, t1i = a0.y - a2.y;
    float t2r = a1.x + a3.x, t2i = a1.y + a3.y;
    float t3r = a1.x - a3.x, t3i = a1.y - a3.y;
    float y0r = t0r + t2r, y0i = t0i + t2i;
    float y1r = t1r + t3i, y1i = t1i - t3r;
    float y2r = t0r - t2r, y2i = t0i - t2i;
    float y3r = t1r - t3i, y3i = t1i + t3r;
    float pq[4];
    pq[0] = fmaxf(y0r*y0r + y0i*y0i, EPSF);
    pq[1] = fmaxf(y1r*y1r + y1i*y1i, EPSF);
    pq[2] = fmaxf(y2r*y2r + y2i*y2i, EPSF);
    pq[3] = fmaxf(y3r*y3r + y3i*y3i, EPSF);
#pragma unroll
    for (int q = 0; q < 4; ++q) {
      psum += pq[q];
      pmax = fmaxf(pmax, pq[q]);
      plog += pq[q] * __logf(pq[q]);
    }
  }
  {
    float r;
    r = wave_red_add(psum);     if (lane == 63) red[68 + wid] = r;
    r = wave_red_max_pos(pmax); if (lane == 63) red[72 + wid] = r;
    r = wave_red_add(plog);     if (lane == 63) red[15*4 + wid] = r;
  }
  __syncthreads();                                   // B6

  // ======== phase G: wave 0 — features, LN, MLP, stores ========
  if (wid == 0) {
    float vsum;
    {
      const float4 q4 = *reinterpret_cast<const float4*>(&red[(lane & 15) * 4]);
      vsum = q4.x + q4.y + q4.z + q4.w;
    }
    const float SUMSQ = readlane_f(vsum, 0);
    float Rk[10];
#pragma unroll
    for (int k = 0; k < 10; ++k) Rk[k] = readlane_f(vsum, 1 + k);
    const float STR   = readlane_f(vsum, 11);
    const float STR2  = readlane_f(vsum, 12);
    const float SC    = readlane_f(vsum, 13);
    const float SC2   = readlane_f(vsum, 14);
    const float PLOGF = readlane_f(vsum, 15);

    const float4 pssv = *reinterpret_cast<const float4*>(&red[68]);
    const float SFULL = pssv.x + pssv.y + pssv.z + pssv.w;
    const float4 pmv = *reinterpret_cast<const float4*>(&red[72]);
    const float PMAX = fmaxf(fmaxf(pmv.x, pmv.y), fmaxf(pmv.z, pmv.w));
    const float4 altv = *reinterpret_cast<const float4*>(&red[64]);
    const float ALT = altv.x + altv.y + altv.z + altv.w;

    const float p0b   = fmaxf(SUMX * SUMX, EPSF);
    const float p512b = fmaxf(ALT * ALT, EPSF);
    const float Sr    = 0.5f * (SFULL + p0b + p512b);
    const float invS  = 1.f / Sr;
    // ent = ln(Sr) - (0.5*(PLOGF + p0*ln p0 + p512*ln p512))/Sr
    const float PLr = 0.5f * (PLOGF + p0b * __logf(p0b) + p512b * __logf(p512b));
    const float ent = __logf(Sr) - PLr * invS;

    const float m = SUMX * (1.f / 1024.f);
    const float den = SUMSQ - 1024.f * m * m + EPSF;
    const float invden = 1.f / den;
    const float4 sa  = *reinterpret_cast<const float4*>(&S[0]);
    const float4 sb  = *reinterpret_cast<const float4*>(&S[4]);
    const float4 sg2 = *reinterpret_cast<const float4*>(&S[8]);
    const float4 sd  = *reinterpret_cast<const float4*>(&S[1012]);
    const float4 se  = *reinterpret_cast<const float4*>(&S[1016]);
    const float4 sf  = *reinterpret_cast<const float4*>(&S[1020]);
    const float Slo[10] = {sa.x,sa.y,sa.z,sa.w, sb.x,sb.y,sb.z,sb.w, sg2.x,sg2.y}; // S[k-1]
    const float Shi[10] = {sf.z,sf.y,sf.x,se.w, se.z,se.y,se.x,sd.w, sd.z,sd.y};   // S[1023-k]
    float acf1 = 0.f, acf2 = 0.f, lbq = 0.f;
#pragma unroll
    for (int k = 1; k <= 10; ++k) {
      float num = Rk[k-1] - m * (Shi[k-1] + (SUMX - Slo[k-1])) + (float)(1024 - k) * m * m;
      float a = fminf(fmaxf(num * invden, -1.f), 1.f);
      if (k == 1) acf1 = a;
      else if (k == 2) acf2 = a;
      lbq += a * a;
    }
    const float spent = fminf(fmaxf(ent / (__logf(513.f + EPSF) + EPSF), 0.f), 1.f);
    const float peak  = fminf(fmaxf(PMAX / (Sr + EPSF), 0.f), 1.f);
    const float R1v = Rk[0];
    const float phi = fminf(fmaxf(R1v / ((SUMSQ - xl * xl) + EPSF), -1.f), 1.f);
    const float invn = 1.f / 1023.f;
    const float sum_d2 = 2.f * SUMSQ - x0 * x0 - xl * xl - 2.f * R1v;
    const float md = (xl - x0) * invn;
    const float diff_var = sum_d2 * invn - md * md;
    const float tstr = STR2 * (1.f / 1024.f) - (STR * (1.f / 1024.f)) * (STR * (1.f / 1024.f));
    const float varx = SUMSQ * (1.f / 1024.f) - m * m;
    const float mc = SC * (1.f / 1024.f);
    const float kpss = (SC2 * (1.f / 1024.f) - mc * mc) / (varx + 1e-8f);

    float f[9] = {acf1, acf2, spent, phi, diff_var, tstr, kpss, lbq, peak};
    float fm = 0.f;
#pragma unroll
    for (int d = 0; d < 9; ++d) fm += f[d];
    fm *= (1.f / 9.f);
    float fv = 0.f;
#pragma unroll
    for (int d = 0; d < 9; ++d) { float t = f[d] - fm; fv += t * t; }
    fv *= (1.f / 9.f);
    const float inl = 1.f / sqrtf(fv + 1e-5f);
    float fn[9];
#pragma unroll
    for (int d = 0; d < 9; ++d) fn[d] = (f[d] - fm) * inl * ln_w[d] + ln_b[d];

    float h = b1[lane];
#pragma unroll
    for (int d = 0; d < 9; ++d) h = fmaf(fn[d], w1[d * 64 + lane], h);
    h = fmaxf(h, 0.f);
    float l0 = h * w2[lane * 3 + 0];
    float l1 = h * w2[lane * 3 + 1];
    float l2 = h * w2[lane * 3 + 2];
    l0 = wave_red_add(l0);
    l1 = wave_red_add(l1);
    l2 = wave_red_add(l2);
    const float L0 = readlane_f(l0, 63) + b2[0];
    const float L1 = readlane_f(l1, 63) + b2[1];
    const float L2 = readlane_f(l2, 63) + b2[2];
    if (lane == 0) {
      const float mx = fmaxf(L0, fmaxf(L1, L2));
      const float e0 = __expf(L0 - mx), e1 = __expf(L1 - mx), e2 = __expf(L2 - mx);
      const float is = 1.f / (e0 + e1 + e2);
      float* o = out + (size_t)row * 3;
      o[0] = e0 * is; o[1] = e1 * is; o[2] = e2 * is;
      float* fo = out + (size_t)B * 3 + (size_t)row * 9;
      fo[0] = fn[0]; fo[1] = fn[1]; fo[2] = fn[2]; fo[3] = fn[3]; fo[4] = fn[4];
      fo[5] = fn[5]; fo[6] = fn[6]; fo[7] = fn[7]; fo[8] = fn[8];
    }
  }
}

extern "C" void kernel_launch(void* const* d_in, const int* in_sizes, int n_in,
                              void* d_out, int out_size, void* d_ws, size_t ws_size,
                              hipStream_t stream) {
  (void)n_in; (void)out_size; (void)d_ws; (void)ws_size;
  const float* x    = (const float*)d_in[0];
  const float* ln_w = (const float*)d_in[1];
  const float* ln_b = (const float*)d_in[2];
  const float* w1   = (const float*)d_in[3];
  const float* b1   = (const float*)d_in[4];
  const float* w2   = (const float*)d_in[5];
  const float* b2   = (const float*)d_in[6];
  float* out = (float*)d_out;
  const int B = in_sizes[0] / 1024;
  sr_kernel<<<B, 256, 0, stream>>>(x, ln_w, ln_b, w1, b1, w2, b2, out, B);
}

// Round 6
// 122.012 us; speedup vs baseline: 3.5009x; 1.3308x over previous
//
#include <hip/hip_runtime.h>
#include <math.h>

#define EPSF 1e-8f

__device__ __forceinline__ float bcf(int x){ return __builtin_bit_cast(float, x); }
__device__ __forceinline__ int   bci(float x){ return __builtin_bit_cast(int, x); }

template<int CTRL, int RM>
__device__ __forceinline__ float dpp0(float v){
  return bcf(__builtin_amdgcn_update_dpp(0, bci(v), CTRL, RM, 0xF, false));
}
__device__ __forceinline__ float rl(float v, int l){
  return bcf(__builtin_amdgcn_readlane(bci(v), l));
}
__device__ __forceinline__ float wave_iscan_add(float v){
  v += dpp0<0x111,0xF>(v);
  v += dpp0<0x112,0xF>(v);
  v += dpp0<0x114,0xF>(v);
  v += dpp0<0x118,0xF>(v);
  v += dpp0<0x142,0xA>(v);
  v += dpp0<0x143,0xC>(v);
  return v;
}
__device__ __forceinline__ float wave_red_add(float v){ return wave_iscan_add(v); } // lane63 = total
__device__ __forceinline__ float wave_red_max_pos(float v){ // v >= 0
  v = fmaxf(v, dpp0<0x111,0xF>(v));
  v = fmaxf(v, dpp0<0x112,0xF>(v));
  v = fmaxf(v, dpp0<0x114,0xF>(v));
  v = fmaxf(v, dpp0<0x118,0xF>(v));
  v = fmaxf(v, dpp0<0x142,0xA>(v));
  v = fmaxf(v, dpp0<0x143,0xC>(v));
  return v;
}

// 8B-unit LDS swizzle; verified 2 lanes/slot (b64 minimum) for all 4 patterns:
// W1 (g*64+t), R1/W2 (g*64+u*16+v*4+c), R2 (t*16+e). Bijective on [0,1024).
__device__ __forceinline__ int FI2(int i){
  return i ^ ((((i >> 6) & 3) << 2) | ((i >> 4) & 3));
}

__global__ void __launch_bounds__(64, 4)
sr_kernel(const float* __restrict__ x,
          const float* __restrict__ ln_w, const float* __restrict__ ln_b,
          const float* __restrict__ w1, const float* __restrict__ b1,
          const float* __restrict__ w2, const float* __restrict__ b2,
          float* __restrict__ out, int B)
{
  __shared__ __align__(16) float2 fc[1024];   // single wave: no __syncthreads anywhere

  const int t = threadIdx.x;                   // 0..63
  const int row = blockIdx.x;
  if (row >= B) return;
  const float* __restrict__ xr = x + (size_t)row * 1024;

  // ---- contiguous ownership: vv[0..15] own, vv[16..27] next-neighbors ----
  const int c0 = t * 16;
  float vv[28];
  {
    const float4 a0 = *reinterpret_cast<const float4*>(xr + c0);
    const float4 a1 = *reinterpret_cast<const float4*>(xr + c0 + 4);
    const float4 a2 = *reinterpret_cast<const float4*>(xr + c0 + 8);
    const float4 a3 = *reinterpret_cast<const float4*>(xr + c0 + 12);
    vv[0]=a0.x; vv[1]=a0.y; vv[2]=a0.z; vv[3]=a0.w;
    vv[4]=a1.x; vv[5]=a1.y; vv[6]=a1.z; vv[7]=a1.w;
    vv[8]=a2.x; vv[9]=a2.y; vv[10]=a2.z; vv[11]=a2.w;
    vv[12]=a3.x; vv[13]=a3.y; vv[14]=a3.z; vv[15]=a3.w;
    if (t < 63) {
      const float4 n0 = *reinterpret_cast<const float4*>(xr + c0 + 16);
      const float4 n1 = *reinterpret_cast<const float4*>(xr + c0 + 20);
      const float4 n2 = *reinterpret_cast<const float4*>(xr + c0 + 24);
      vv[16]=n0.x; vv[17]=n0.y; vv[18]=n0.z; vv[19]=n0.w;
      vv[20]=n1.x; vv[21]=n1.y; vv[22]=n1.z; vv[23]=n1.w;
      vv[24]=n2.x; vv[25]=n2.y; vv[26]=n2.z; vv[27]=n2.w;
    } else {
#pragma unroll
      for (int j = 16; j < 28; ++j) vv[j] = 0.f;
    }
  }
  float pv[12];   // x[c0-12 .. c0-1], zeros for t==0 (acts as S<0 guard)
  if (t > 0) {
    const float4 p0 = *reinterpret_cast<const float4*>(xr + c0 - 12);
    const float4 p1 = *reinterpret_cast<const float4*>(xr + c0 - 8);
    const float4 p2 = *reinterpret_cast<const float4*>(xr + c0 - 4);
    pv[0]=p0.x; pv[1]=p0.y; pv[2]=p0.z; pv[3]=p0.w;
    pv[4]=p1.x; pv[5]=p1.y; pv[6]=p1.z; pv[7]=p1.w;
    pv[8]=p2.x; pv[9]=p2.y; pv[10]=p2.z; pv[11]=p2.w;
  } else {
#pragma unroll
    for (int j = 0; j < 12; ++j) pv[j] = 0.f;
  }

  // ---- per-thread stats ----
  float sumsq = 0.f, alt = 0.f;
#pragma unroll
  for (int j = 0; j < 16; ++j) {
    sumsq = fmaf(vv[j], vv[j], sumsq);
    alt += (j & 1) ? -vv[j] : vv[j];
  }
  float Rp[10];
#pragma unroll
  for (int k = 1; k <= 10; ++k) {
    float r = 0.f;
#pragma unroll
    for (int j = 0; j < 16; ++j) r = fmaf(vv[j], vv[j + k], r);
    Rp[k-1] = r;
  }
  const float SUMSQ = rl(wave_red_add(sumsq), 63);
  const float ALT   = rl(wave_red_add(alt), 63);
  float Rk[10];
#pragma unroll
  for (int k = 0; k < 10; ++k) Rk[k] = rl(wave_red_add(Rp[k]), 63);

  // ---- prefix sums (registers + wave scan) ----
  float s[16];
  s[0] = vv[0];
#pragma unroll
  for (int j = 1; j < 16; ++j) s[j] = s[j-1] + vv[j];
  const float cs16 = s[15];
  const float incl = wave_iscan_add(cs16);
  const float excl = incl - cs16;
#pragma unroll
  for (int j = 0; j < 16; ++j) s[j] += excl;
  const float SUMX = rl(incl, 63);
  const float x0 = rl(vv[0], 0);
  const float xl = rl(vv[15], 63);
  float Slo[10], Shi[10];
#pragma unroll
  for (int q = 0; q < 10; ++q) Slo[q] = rl(s[q], 0);        // S_incl[q]   = ps[q+1]
#pragma unroll
  for (int k = 1; k <= 10; ++k) Shi[k-1] = rl(s[15-k], 63); // S_incl[1023-k] = ps[1024-k]

  // ---- trend via sliding +-12 window over register data ----
  float trv[16];
  float str = 0.f, str2 = 0.f;
  {
    float wsum = 0.f;
#pragma unroll
    for (int j = 0; j < 12; ++j) wsum += pv[j];
#pragma unroll
    for (int j = 0; j <= 12; ++j) wsum += vv[j];
#pragma unroll
    for (int jj = 0; jj < 16; ++jj) {
      if (jj > 0) {
        const float addv = vv[jj + 12];                       // x[c0+jj+12]
        const float subv = (jj < 13) ? pv[jj - 1] : vv[jj - 13]; // x[c0+jj-13]
        wsum += addv - subv;
      }
      float swc = wsum;
      if (t == 0  && jj < 12) swc += (float)(12 - jj) * x0;
      if (t == 63 && jj >= 4) swc += (float)(jj - 3) * xl;
      const float tv = swc * 0.04f;
      trv[jj] = tv;
      str += tv;
      str2 = fmaf(tv, tv, str2);
    }
  }
  const float tincl = wave_iscan_add(str);
  const float texcl = tincl - str;
  float run = texcl, sc = 0.f, sc2 = 0.f;
#pragma unroll
  for (int jj = 0; jj < 16; ++jj) {
    run += trv[jj];
    const float cv = s[jj] - run;          // cumsum(resid)[c0+jj]
    sc += cv;
    sc2 = fmaf(cv, cv, sc2);
  }
  const float STR  = rl(tincl, 63);
  const float STR2 = rl(wave_red_add(str2), 63);
  const float SC   = rl(wave_red_add(sc), 63);
  const float SC2  = rl(wave_red_add(sc2), 63);

  // ---- strided reload for FFT ownership (L1/L2 hit, vm pipe) ----
  float xs[4][4];
#pragma unroll
  for (int a = 0; a < 4; ++a)
#pragma unroll
    for (int b = 0; b < 4; ++b)
      xs[a][b] = xr[(a << 8) + (b << 6) + t];

  // twiddle constant tables (compile-time)
  constexpr float C22 = 0.9238795325112867f, S22 = 0.3826834323650898f, C45 = 0.7071067811865476f;
  const float OB1r[4] = {1.f,  C22,  C45,  S22};
  const float OB1i[4] = {0.f, -S22, -C45, -C22};
  const float OB2r[4] = {1.f,  C45,  0.f, -C45};
  const float OB2i[4] = {0.f, -C45, -1.f, -C45};
  const float OB3r[4] = {1.f,  S22, -C45, -C22};
  const float OB3i[4] = {0.f, -C22, -C45,  S22};

  // ---- FFT stage 1 (LEN=1024, real inputs) in registers ----
  const float ang1 = -0.0061359231515425649f * (float)t;   // -2pi/1024 * t
  const float c1t = __cosf(ang1), s1t = __sinf(ang1);
  const float c2t = c1t*c1t - s1t*s1t, s2t = 2.f*c1t*s1t;
  const float c3t = c1t*c2t - s1t*s2t, s3t = s1t*c2t + c1t*s2t;
  float fRr[4][4], fRi[4][4];   // [a][b]
#pragma unroll
  for (int b = 0; b < 4; ++b) {
    const float tw1r = c1t*OB1r[b] - s1t*OB1i[b], tw1i = c1t*OB1i[b] + s1t*OB1r[b];
    const float tw2r = c2t*OB2r[b] - s2t*OB2i[b], tw2i = c2t*OB2i[b] + s2t*OB2r[b];
    const float tw3r = c3t*OB3r[b] - s3t*OB3i[b], tw3i = c3t*OB3i[b] + s3t*OB3r[b];
    const float X0 = xs[0][b], X1 = xs[1][b], X2 = xs[2][b], X3 = xs[3][b];
    const float t0 = X0 + X2, t1 = X0 - X2, t2 = X1 + X3, t3 = X1 - X3;
    fRr[0][b] = t0 + t2;                 fRi[0][b] = 0.f;
    fRr[1][b] = t1*tw1r + t3*tw1i;       fRi[1][b] = t1*tw1i - t3*tw1r;   // (t1,-t3)*tw1
    const float y2 = t0 - t2;
    fRr[2][b] = y2*tw2r;                 fRi[2][b] = y2*tw2i;
    fRr[3][b] = t1*tw3r - t3*tw3i;       fRi[3][b] = t1*tw3i + t3*tw3r;   // (t1, t3)*tw3
  }

  // ---- FFT stage 2 (LEN=256), twiddles w256^t = w_t^4 via recurrence ----
  const float c4 = c2t*c2t - s2t*s2t,  s4 = 2.f*c2t*s2t;
  const float c8 = c4*c4 - s4*s4,      s8 = 2.f*c4*s4;
  const float c12 = c4*c8 - s4*s8,     s12 = s4*c8 + c4*s8;
#pragma unroll
  for (int a = 0; a < 4; ++a) {
    const float A0r=fRr[a][0], A0i=fRi[a][0], A1r=fRr[a][1], A1i=fRi[a][1];
    const float A2r=fRr[a][2], A2i=fRi[a][2], A3r=fRr[a][3], A3i=fRi[a][3];
    const float t0r=A0r+A2r, t0i=A0i+A2i, t1r=A0r-A2r, t1i=A0i-A2i;
    const float t2r=A1r+A3r, t2i=A1i+A3i, t3r=A1r-A3r, t3i=A1i-A3i;
    fRr[a][0] = t0r + t2r;  fRi[a][0] = t0i + t2i;
    const float y1r = t1r + t3i, y1i = t1i - t3r;
    fRr[a][1] = y1r*c4 - y1i*s4;    fRi[a][1] = y1r*s4 + y1i*c4;
    const float y2r = t0r - t2r, y2i = t0i - t2i;
    fRr[a][2] = y2r*c8 - y2i*s8;    fRi[a][2] = y2r*s8 + y2i*c8;
    const float y3r = t1r - t3i, y3i = t1i + t3r;
    fRr[a][3] = y3r*c12 - y3i*s12;  fRi[a][3] = y3r*s12 + y3i*c12;
  }

  // ---- shuffle 1: location (a*4+b)*64 + t ----
#pragma unroll
  for (int a = 0; a < 4; ++a)
#pragma unroll
    for (int b = 0; b < 4; ++b)
      fc[FI2(((a*4+b) << 6) + t)] = make_float2(fRr[a][b], fRi[a][b]);

  const int g = t >> 2, cc = t & 3;
  const int gb = g << 6;
  float yrr[4][4], yii[4][4];   // [u][v]
#pragma unroll
  for (int u = 0; u < 4; ++u)
#pragma unroll
    for (int v = 0; v < 4; ++v) {
      const float2 z = fc[FI2(gb + u*16 + v*4 + cc)];
      yrr[u][v] = z.x; yii[u][v] = z.y;
    }

  // ---- FFT stage 3 (LEN=64): tw1 = w64^cc * w16^v ----
  const float angc = -0.09817477042468103f * (float)cc;    // -2pi/64 * cc
  const float wc1r = __cosf(angc), wc1i = __sinf(angc);
#pragma unroll
  for (int v = 0; v < 4; ++v) {
    const float t1r_ = wc1r*OB1r[v] - wc1i*OB1i[v];
    const float t1i_ = wc1r*OB1i[v] + wc1i*OB1r[v];
    const float t2r_ = t1r_*t1r_ - t1i_*t1i_;
    const float t2i_ = 2.f*t1r_*t1i_;
    const float t3r_ = t1r_*t2r_ - t1i_*t2i_;
    const float t3i_ = t1i_*t2r_ + t1r_*t2i_;
    const float A0r=yrr[0][v], A0i=yii[0][v], A1r=yrr[1][v], A1i=yii[1][v];
    const float A2r=yrr[2][v], A2i=yii[2][v], A3r=yrr[3][v], A3i=yii[3][v];
    const float t0r=A0r+A2r, t0i=A0i+A2i, t1r=A0r-A2r, t1i=A0i-A2i;
    const float t2r=A1r+A3r, t2i=A1i+A3i, t3r=A1r-A3r, t3i=A1i-A3i;
    yrr[0][v] = t0r + t2r;  yii[0][v] = t0i + t2i;
    const float y1r = t1r + t3i, y1i = t1i - t3r;
    yrr[1][v] = y1r*t1r_ - y1i*t1i_;  yii[1][v] = y1r*t1i_ + y1i*t1r_;
    const float y2r = t0r - t2r, y2i = t0i - t2i;
    yrr[2][v] = y2r*t2r_ - y2i*t2i_;  yii[2][v] = y2r*t2i_ + y2i*t2r_;
    const float y3r = t1r - t3i, y3i = t1i + t3r;
    yrr[3][v] = y3r*t3r_ - y3i*t3i_;  yii[3][v] = y3r*t3i_ + y3i*t3r_;
  }

  // ---- FFT stage 4 (LEN=16): tw = w16^cc = (w64^cc)^4 via recurrence ----
  const float q2r = wc1r*wc1r - wc1i*wc1i, q2i = 2.f*wc1r*wc1i;
  const float w4r = q2r*q2r - q2i*q2i,     w4i = 2.f*q2r*q2i;
  const float w8r = w4r*w4r - w4i*w4i,     w8i = 2.f*w4r*w4i;
  const float w12r = w4r*w8r - w4i*w8i,    w12i = w4i*w8r + w4r*w8i;
#pragma unroll
  for (int u = 0; u < 4; ++u) {
    const float A0r=yrr[u][0], A0i=yii[u][0], A1r=yrr[u][1], A1i=yii[u][1];
    const float A2r=yrr[u][2], A2i=yii[u][2], A3r=yrr[u][3], A3i=yii[u][3];
    const float t0r=A0r+A2r, t0i=A0i+A2i, t1r=A0r-A2r, t1i=A0i-A2i;
    const float t2r=A1r+A3r, t2i=A1i+A3i, t3r=A1r-A3r, t3i=A1i-A3i;
    yrr[u][0] = t0r + t2r;  yii[u][0] = t0i + t2i;
    const float y1r = t1r + t3i, y1i = t1i - t3r;
    yrr[u][1] = y1r*w4r - y1i*w4i;    yii[u][1] = y1r*w4i + y1i*w4r;
    const float y2r = t0r - t2r, y2i = t0i - t2i;
    yrr[u][2] = y2r*w8r - y2i*w8i;    yii[u][2] = y2r*w8i + y2i*w8r;
    const float y3r = t1r - t3i, y3i = t1i + t3r;
    yrr[u][3] = y3r*w12r - y3i*w12i;  yii[u][3] = y3r*w12i + y3i*w12r;
  }

  // ---- shuffle 2 (write back), then contiguous read + fused stage 5 + psd ----
#pragma unroll
  for (int u = 0; u < 4; ++u)
#pragma unroll
    for (int v = 0; v < 4; ++v)
      fc[FI2(gb + u*16 + v*4 + cc)] = make_float2(yrr[u][v], yii[u][v]);

  float psum = 0.f, pmax = 0.f, plog = 0.f;
  const int m0 = t << 4;
#pragma unroll
  for (int q = 0; q < 4; ++q) {
    const float2 z0 = fc[FI2(m0 + q*4 + 0)];
    const float2 z1 = fc[FI2(m0 + q*4 + 1)];
    const float2 z2 = fc[FI2(m0 + q*4 + 2)];
    const float2 z3 = fc[FI2(m0 + q*4 + 3)];
    const float t0r=z0.x+z2.x, t0i=z0.y+z2.y, t1r=z0.x-z2.x, t1i=z0.y-z2.y;
    const float t2r=z1.x+z3.x, t2i=z1.y+z3.y, t3r=z1.x-z3.x, t3i=z1.y-z3.y;
    const float y0r=t0r+t2r, y0i=t0i+t2i;
    const float y1r=t1r+t3i, y1i=t1i-t3r;
    const float y2r=t0r-t2r, y2i=t0i-t2i;
    const float y3r=t1r-t3i, y3i=t1i+t3r;
    const float pp0 = fmaxf(y0r*y0r + y0i*y0i, EPSF);
    const float pp1 = fmaxf(y1r*y1r + y1i*y1i, EPSF);
    const float pp2 = fmaxf(y2r*y2r + y2i*y2i, EPSF);
    const float pp3 = fmaxf(y3r*y3r + y3i*y3i, EPSF);
    psum += pp0 + pp1 + pp2 + pp3;
    pmax = fmaxf(fmaxf(pmax, pp0), fmaxf(pp1, pp2));
    pmax = fmaxf(pmax, pp3);
    plog += pp0*__logf(pp0) + pp1*__logf(pp1) + pp2*__logf(pp2) + pp3*__logf(pp3);
  }
  const float PSUM = rl(wave_red_add(psum), 63);
  const float PMAX = rl(wave_red_max_pos(pmax), 63);
  const float PLOG = rl(wave_red_add(plog), 63);

  // ---- features (uniform across the wave) ----
  const float p0b   = fmaxf(SUMX * SUMX, EPSF);
  const float p512b = fmaxf(ALT * ALT, EPSF);
  const float Sr    = 0.5f * (PSUM + p0b + p512b);
  const float invS  = 1.f / Sr;
  const float PLr   = 0.5f * (PLOG + p0b*__logf(p0b) + p512b*__logf(p512b));
  const float ent   = __logf(Sr) - PLr * invS;

  const float m = SUMX * (1.f / 1024.f);
  const float den = SUMSQ - 1024.f * m * m + EPSF;
  const float invden = 1.f / den;
  float acf1 = 0.f, acf2 = 0.f, lbq = 0.f;
#pragma unroll
  for (int k = 1; k <= 10; ++k) {
    const float num = Rk[k-1] - m * (Shi[k-1] + (SUMX - Slo[k-1])) + (float)(1024 - k) * m * m;
    const float a = fminf(fmaxf(num * invden, -1.f), 1.f);
    if (k == 1) acf1 = a;
    else if (k == 2) acf2 = a;
    lbq += a * a;
  }
  const float spent = fminf(fmaxf(ent / (__logf(513.f + EPSF) + EPSF), 0.f), 1.f);
  const float peak  = fminf(fmaxf(PMAX / (Sr + EPSF), 0.f), 1.f);
  const float R1v = Rk[0];
  const float phi = fminf(fmaxf(R1v / ((SUMSQ - xl * xl) + EPSF), -1.f), 1.f);
  const float invn = 1.f / 1023.f;
  const float sum_d2 = 2.f * SUMSQ - x0 * x0 - xl * xl - 2.f * R1v;
  const float md = (xl - x0) * invn;
  const float diff_var = sum_d2 * invn - md * md;
  const float tstr = STR2 * (1.f / 1024.f) - (STR * (1.f / 1024.f)) * (STR * (1.f / 1024.f));
  const float varx = SUMSQ * (1.f / 1024.f) - m * m;
  const float mc = SC * (1.f / 1024.f);
  const float kpss = (SC2 * (1.f / 1024.f) - mc * mc) / (varx + 1e-8f);

  float f[9] = {acf1, acf2, spent, phi, diff_var, tstr, kpss, lbq, peak};
  float fm = 0.f;
#pragma unroll
  for (int d = 0; d < 9; ++d) fm += f[d];
  fm *= (1.f / 9.f);
  float fv = 0.f;
#pragma unroll
  for (int d = 0; d < 9; ++d) { const float tt = f[d] - fm; fv = fmaf(tt, tt, fv); }
  fv *= (1.f / 9.f);
  const float inl = 1.f / sqrtf(fv + 1e-5f);
  float fn[9];
#pragma unroll
  for (int d = 0; d < 9; ++d) fn[d] = (f[d] - fm) * inl * ln_w[d] + ln_b[d];

  // ---- MLP: hidden unit = lane ----
  float h = b1[t];
#pragma unroll
  for (int d = 0; d < 9; ++d) h = fmaf(fn[d], w1[d * 64 + t], h);
  h = fmaxf(h, 0.f);
  float l0 = h * w2[t * 3 + 0];
  float l1 = h * w2[t * 3 + 1];
  float l2 = h * w2[t * 3 + 2];
  l0 = wave_red_add(l0);
  l1 = wave_red_add(l1);
  l2 = wave_red_add(l2);
  const float L0 = rl(l0, 63) + b2[0];
  const float L1 = rl(l1, 63) + b2[1];
  const float L2 = rl(l2, 63) + b2[2];
  if (t == 0) {
    const float mx = fmaxf(L0, fmaxf(L1, L2));
    const float e0 = __expf(L0 - mx), e1 = __expf(L1 - mx), e2 = __expf(L2 - mx);
    const float is = 1.f / (e0 + e1 + e2);
    float* o = out + (size_t)row * 3;
    o[0] = e0 * is; o[1] = e1 * is; o[2] = e2 * is;
    float* fo = out + (size_t)B * 3 + (size_t)row * 9;
    fo[0] = fn[0]; fo[1] = fn[1]; fo[2] = fn[2]; fo[3] = fn[3]; fo[4] = fn[4];
    fo[5] = fn[5]; fo[6] = fn[6]; fo[7] = fn[7]; fo[8] = fn[8];
  }
}

extern "C" void kernel_launch(void* const* d_in, const int* in_sizes, int n_in,
                              void* d_out, int out_size, void* d_ws, size_t ws_size,
                              hipStream_t stream) {
  (void)n_in; (void)out_size; (void)d_ws; (void)ws_size;
  const float* x    = (const float*)d_in[0];
  const float* ln_w = (const float*)d_in[1];
  const float* ln_b = (const float*)d_in[2];
  const float* w1   = (const float*)d_in[3];
  const float* b1   = (const float*)d_in[4];
  const float* w2   = (const float*)d_in[5];
  const float* b2   = (const float*)d_in[6];
  float* out = (float*)d_out;
  const int B = in_sizes[0] / 1024;
  sr_kernel<<<B, 64, 0, stream>>>(x, ln_w, ln_b, w1, b1, w2, b2, out, B);
}

// Round 7
// 111.852 us; speedup vs baseline: 3.8189x; 1.0908x over previous
//
#include <hip/hip_runtime.h>
#include <math.h>

#define EPSF 1e-8f

__device__ __forceinline__ float bcf(int x){ return __builtin_bit_cast(float, x); }
__device__ __forceinline__ int   bci(float x){ return __builtin_bit_cast(int, x); }

template<int CTRL, int RM>
__device__ __forceinline__ float dpp0(float v){
  return bcf(__builtin_amdgcn_update_dpp(0, bci(v), CTRL, RM, 0xF, false));
}
__device__ __forceinline__ float rl(float v, int l){
  return bcf(__builtin_amdgcn_readlane(bci(v), l));
}
__device__ __forceinline__ float wave_iscan_add(float v){
  v += dpp0<0x111,0xF>(v);
  v += dpp0<0x112,0xF>(v);
  v += dpp0<0x114,0xF>(v);
  v += dpp0<0x118,0xF>(v);
  v += dpp0<0x142,0xA>(v);
  v += dpp0<0x143,0xC>(v);
  return v;
}
__device__ __forceinline__ float wave_red_add(float v){ return wave_iscan_add(v); } // lane63 = total
__device__ __forceinline__ float wave_red_max_pos(float v){ // v >= 0
  v = fmaxf(v, dpp0<0x111,0xF>(v));
  v = fmaxf(v, dpp0<0x112,0xF>(v));
  v = fmaxf(v, dpp0<0x114,0xF>(v));
  v = fmaxf(v, dpp0<0x118,0xF>(v));
  v = fmaxf(v, dpp0<0x142,0xA>(v));
  v = fmaxf(v, dpp0<0x143,0xC>(v));
  return v;
}

// 8B-unit LDS swizzle; 2 lanes/slot (b64 minimum) for all 4 patterns. Bijective on [0,1024).
__device__ __forceinline__ int FI2(int i){
  return i ^ ((((i >> 6) & 3) << 2) | ((i >> 4) & 3));
}

// stats LDS slots (per wave)
// 0 SUMSQ, 1 ALT, 2..11 R1..R10, 12 STR, 13 STR2, 14 SC, 15 SC2, 16 SUMX,
// 17..26 Slo[0..9] (=ps[1..10]), 27..36 s[5..14] (Shi(k)=stats[37-k]), 37 x0, 38 xl
__global__ void __launch_bounds__(128, 2)
sr_kernel(const float* __restrict__ x,
          const float* __restrict__ ln_w, const float* __restrict__ ln_b,
          const float* __restrict__ w1, const float* __restrict__ b1,
          const float* __restrict__ w2, const float* __restrict__ b2,
          float* __restrict__ out, int B)
{
  __shared__ __align__(16) float2 fc2[2][1024];
  __shared__ __align__(16) float stats2[2][40];

  const int tid = threadIdx.x;
  const int t   = tid & 63;          // lane
  const int wv  = tid >> 6;          // wave in block
  const int row = blockIdx.x * 2 + wv;
  if (row >= B) return;
  const float* __restrict__ xr = x + (size_t)row * 1024;
  float2* fc = fc2[wv];
  float*  st = stats2[wv];

  // ---- contiguous ownership: vv[0..15] own, vv[16..27] next-neighbors ----
  const int c0 = t * 16;
  float vv[28];
  {
    const float4 a0 = *reinterpret_cast<const float4*>(xr + c0);
    const float4 a1 = *reinterpret_cast<const float4*>(xr + c0 + 4);
    const float4 a2 = *reinterpret_cast<const float4*>(xr + c0 + 8);
    const float4 a3 = *reinterpret_cast<const float4*>(xr + c0 + 12);
    vv[0]=a0.x; vv[1]=a0.y; vv[2]=a0.z; vv[3]=a0.w;
    vv[4]=a1.x; vv[5]=a1.y; vv[6]=a1.z; vv[7]=a1.w;
    vv[8]=a2.x; vv[9]=a2.y; vv[10]=a2.z; vv[11]=a2.w;
    vv[12]=a3.x; vv[13]=a3.y; vv[14]=a3.z; vv[15]=a3.w;
    if (t < 63) {
      const float4 n0 = *reinterpret_cast<const float4*>(xr + c0 + 16);
      const float4 n1 = *reinterpret_cast<const float4*>(xr + c0 + 20);
      const float4 n2 = *reinterpret_cast<const float4*>(xr + c0 + 24);
      vv[16]=n0.x; vv[17]=n0.y; vv[18]=n0.z; vv[19]=n0.w;
      vv[20]=n1.x; vv[21]=n1.y; vv[22]=n1.z; vv[23]=n1.w;
      vv[24]=n2.x; vv[25]=n2.y; vv[26]=n2.z; vv[27]=n2.w;
    } else {
#pragma unroll
      for (int j = 16; j < 28; ++j) vv[j] = 0.f;
    }
  }
  float pv[12];   // x[c0-12 .. c0-1], zeros for t==0
  if (t > 0) {
    const float4 p0 = *reinterpret_cast<const float4*>(xr + c0 - 12);
    const float4 p1 = *reinterpret_cast<const float4*>(xr + c0 - 8);
    const float4 p2 = *reinterpret_cast<const float4*>(xr + c0 - 4);
    pv[0]=p0.x; pv[1]=p0.y; pv[2]=p0.z; pv[3]=p0.w;
    pv[4]=p1.x; pv[5]=p1.y; pv[6]=p1.z; pv[7]=p1.w;
    pv[8]=p2.x; pv[9]=p2.y; pv[10]=p2.z; pv[11]=p2.w;
  } else {
#pragma unroll
    for (int j = 0; j < 12; ++j) pv[j] = 0.f;
  }

  // ---- per-thread stats; reductions stashed to LDS from lane 63 ----
  float sumsq = 0.f, alt = 0.f;
#pragma unroll
  for (int j = 0; j < 16; ++j) {
    sumsq = fmaf(vv[j], vv[j], sumsq);
    alt += (j & 1) ? -vv[j] : vv[j];
  }
  {
    float r;
    r = wave_red_add(sumsq); if (t == 63) st[0] = r;
    r = wave_red_add(alt);   if (t == 63) st[1] = r;
  }
#pragma unroll
  for (int k = 1; k <= 10; ++k) {
    float r = 0.f;
#pragma unroll
    for (int j = 0; j < 16; ++j) r = fmaf(vv[j], vv[j + k], r);
    r = wave_red_add(r);
    if (t == 63) st[1 + k] = r;
  }

  // ---- prefix sums ----
  float s[16];
  s[0] = vv[0];
#pragma unroll
  for (int j = 1; j < 16; ++j) s[j] = s[j-1] + vv[j];
  const float cs16 = s[15];
  const float incl = wave_iscan_add(cs16);
  const float excl = incl - cs16;
#pragma unroll
  for (int j = 0; j < 16; ++j) s[j] += excl;
  if (t == 63) st[16] = incl;                       // SUMX
  if (t == 0) {
#pragma unroll
    for (int q = 0; q < 10; ++q) st[17 + q] = s[q]; // Slo
    st[37] = vv[0];                                  // x0
  }
  if (t == 63) {
#pragma unroll
    for (int q = 0; q < 10; ++q) st[27 + q] = s[5 + q]; // Shi pool
    st[38] = vv[15];                                 // xl
  }

  // ---- trend via sliding +-12 window ----
  float trv[16];
  float str = 0.f, str2 = 0.f;
  {
    float wsum = 0.f;
#pragma unroll
    for (int j = 0; j < 12; ++j) wsum += pv[j];
#pragma unroll
    for (int j = 0; j <= 12; ++j) wsum += vv[j];
#pragma unroll
    for (int jj = 0; jj < 16; ++jj) {
      if (jj > 0) {
        const float addv = vv[jj + 12];
        const float subv = (jj < 13) ? pv[jj - 1] : vv[jj - 13];
        wsum += addv - subv;
      }
      float swc = wsum;
      if (t == 0  && jj < 12) swc += (float)(12 - jj) * vv[0];
      if (t == 63 && jj >= 4) swc += (float)(jj - 3) * vv[15];
      const float tv = swc * 0.04f;
      trv[jj] = tv;
      str += tv;
      str2 = fmaf(tv, tv, str2);
    }
  }
  const float tincl = wave_iscan_add(str);
  if (t == 63) st[12] = tincl;                       // STR
  { float r = wave_red_add(str2); if (t == 63) st[13] = r; }
  {
    const float texcl = tincl - str;
    float run = texcl, sc = 0.f, sc2 = 0.f;
#pragma unroll
    for (int jj = 0; jj < 16; ++jj) {
      run += trv[jj];
      const float cv = s[jj] - run;
      sc += cv;
      sc2 = fmaf(cv, cv, sc2);
    }
    float r;
    r = wave_red_add(sc);  if (t == 63) st[14] = r;
    r = wave_red_add(sc2); if (t == 63) st[15] = r;
  }

  // ---- strided reload for FFT ownership ----
  float xs[4][4];
#pragma unroll
  for (int a = 0; a < 4; ++a)
#pragma unroll
    for (int b = 0; b < 4; ++b)
      xs[a][b] = xr[(a << 8) + (b << 6) + t];

  constexpr float C22 = 0.9238795325112867f, S22 = 0.3826834323650898f, C45 = 0.7071067811865476f;
  const float OB1r[4] = {1.f,  C22,  C45,  S22};
  const float OB1i[4] = {0.f, -S22, -C45, -C22};
  const float OB2r[4] = {1.f,  C45,  0.f, -C45};
  const float OB2i[4] = {0.f, -C45, -1.f, -C45};
  const float OB3r[4] = {1.f,  S22, -C45, -C22};
  const float OB3i[4] = {0.f, -C22, -C45,  S22};

  // ---- FFT stage 1 (LEN=1024, real inputs) ----
  const float ang1 = -0.0061359231515425649f * (float)t;
  const float c1t = __cosf(ang1), s1t = __sinf(ang1);
  const float c2t = c1t*c1t - s1t*s1t, s2t = 2.f*c1t*s1t;
  const float c3t = c1t*c2t - s1t*s2t, s3t = s1t*c2t + c1t*s2t;
  float fRr[4][4], fRi[4][4];
#pragma unroll
  for (int b = 0; b < 4; ++b) {
    const float tw1r = c1t*OB1r[b] - s1t*OB1i[b], tw1i = c1t*OB1i[b] + s1t*OB1r[b];
    const float tw2r = c2t*OB2r[b] - s2t*OB2i[b], tw2i = c2t*OB2i[b] + s2t*OB2r[b];
    const float tw3r = c3t*OB3r[b] - s3t*OB3i[b], tw3i = c3t*OB3i[b] + s3t*OB3r[b];
    const float X0 = xs[0][b], X1 = xs[1][b], X2 = xs[2][b], X3 = xs[3][b];
    const float t0 = X0 + X2, t1 = X0 - X2, t2 = X1 + X3, t3 = X1 - X3;
    fRr[0][b] = t0 + t2;                 fRi[0][b] = 0.f;
    fRr[1][b] = t1*tw1r + t3*tw1i;       fRi[1][b] = t1*tw1i - t3*tw1r;
    const float y2 = t0 - t2;
    fRr[2][b] = y2*tw2r;                 fRi[2][b] = y2*tw2i;
    fRr[3][b] = t1*tw3r - t3*tw3i;       fRi[3][b] = t1*tw3i + t3*tw3r;
  }

  // ---- FFT stage 2 (LEN=256) ----
  const float c4 = c2t*c2t - s2t*s2t,  s4 = 2.f*c2t*s2t;
  const float c8 = c4*c4 - s4*s4,      s8 = 2.f*c4*s4;
  const float c12 = c4*c8 - s4*s8,     s12 = s4*c8 + c4*s8;
#pragma unroll
  for (int a = 0; a < 4; ++a) {
    const float A0r=fRr[a][0], A0i=fRi[a][0], A1r=fRr[a][1], A1i=fRi[a][1];
    const float A2r=fRr[a][2], A2i=fRi[a][2], A3r=fRr[a][3], A3i=fRi[a][3];
    const float t0r=A0r+A2r, t0i=A0i+A2i, t1r=A0r-A2r, t1i=A0i-A2i;
    const float t2r=A1r+A3r, t2i=A1i+A3i, t3r=A1r-A3r, t3i=A1i-A3i;
    fRr[a][0] = t0r + t2r;  fRi[a][0] = t0i + t2i;
    const float y1r = t1r + t3i, y1i = t1i - t3r;
    fRr[a][1] = y1r*c4 - y1i*s4;    fRi[a][1] = y1r*s4 + y1i*c4;
    const float y2r = t0r - t2r, y2i = t0i - t2i;
    fRr[a][2] = y2r*c8 - y2i*s8;    fRi[a][2] = y2r*s8 + y2i*c8;
    const float y3r = t1r - t3i, y3i = t1i + t3r;
    fRr[a][3] = y3r*c12 - y3i*s12;  fRi[a][3] = y3r*s12 + y3i*c12;
  }

  // ---- shuffle 1 ----
#pragma unroll
  for (int a = 0; a < 4; ++a)
#pragma unroll
    for (int b = 0; b < 4; ++b)
      fc[FI2(((a*4+b) << 6) + t)] = make_float2(fRr[a][b], fRi[a][b]);

  const int g = t >> 2, cc = t & 3;
  const int gb = g << 6;
  float yrr[4][4], yii[4][4];
#pragma unroll
  for (int u = 0; u < 4; ++u)
#pragma unroll
    for (int v = 0; v < 4; ++v) {
      const float2 z = fc[FI2(gb + u*16 + v*4 + cc)];
      yrr[u][v] = z.x; yii[u][v] = z.y;
    }

  // ---- FFT stage 3 (LEN=64) ----
  const float angc = -0.09817477042468103f * (float)cc;
  const float wc1r = __cosf(angc), wc1i = __sinf(angc);
#pragma unroll
  for (int v = 0; v < 4; ++v) {
    const float t1r_ = wc1r*OB1r[v] - wc1i*OB1i[v];
    const float t1i_ = wc1r*OB1i[v] + wc1i*OB1r[v];
    const float t2r_ = t1r_*t1r_ - t1i_*t1i_;
    const float t2i_ = 2.f*t1r_*t1i_;
    const float t3r_ = t1r_*t2r_ - t1i_*t2i_;
    const float t3i_ = t1i_*t2r_ + t1r_*t2i_;
    const float A0r=yrr[0][v], A0i=yii[0][v], A1r=yrr[1][v], A1i=yii[1][v];
    const float A2r=yrr[2][v], A2i=yii[2][v], A3r=yrr[3][v], A3i=yii[3][v];
    const float t0r=A0r+A2r, t0i=A0i+A2i, t1r=A0r-A2r, t1i=A0i-A2i;
    const float t2r=A1r+A3r, t2i=A1i+A3i, t3r=A1r-A3r, t3i=A1i-A3i;
    yrr[0][v] = t0r + t2r;  yii[0][v] = t0i + t2i;
    const float y1r = t1r + t3i, y1i = t1i - t3r;
    yrr[1][v] = y1r*t1r_ - y1i*t1i_;  yii[1][v] = y1r*t1i_ + y1i*t1r_;
    const float y2r = t0r - t2r, y2i = t0i - t2i;
    yrr[2][v] = y2r*t2r_ - y2i*t2i_;  yii[2][v] = y2r*t2i_ + y2i*t2r_;
    const float y3r = t1r - t3i, y3i = t1i + t3r;
    yrr[3][v] = y3r*t3r_ - y3i*t3i_;  yii[3][v] = y3r*t3i_ + y3i*t3r_;
  }

  // ---- FFT stage 4 (LEN=16) ----
  const float q2r = wc1r*wc1r - wc1i*wc1i, q2i = 2.f*wc1r*wc1i;
  const float w4r = q2r*q2r - q2i*q2i,     w4i = 2.f*q2r*q2i;
  const float w8r = w4r*w4r - w4i*w4i,     w8i = 2.f*w4r*w4i;
  const float w12r = w4r*w8r - w4i*w8i,    w12i = w4i*w8r + w4r*w8i;
#pragma unroll
  for (int u = 0; u < 4; ++u) {
    const float A0r=yrr[u][0], A0i=yii[u][0], A1r=yrr[u][1], A1i=yii[u][1];
    const float A2r=yrr[u][2], A2i=yii[u][2], A3r=yrr[u][3], A3i=yii[u][3];
    const float t0r=A0r+A2r, t0i=A0i+A2i, t1r=A0r-A2r, t1i=A0i-A2i;
    const float t2r=A1r+A3r, t2i=A1i+A3i, t3r=A1r-A3r, t3i=A1i-A3i;
    yrr[u][0] = t0r + t2r;  yii[u][0] = t0i + t2i;
    const float y1r = t1r + t3i, y1i = t1i - t3r;
    yrr[u][1] = y1r*w4r - y1i*w4i;    yii[u][1] = y1r*w4i + y1i*w4r;
    const float y2r = t0r - t2r, y2i = t0i - t2i;
    yrr[u][2] = y2r*w8r - y2i*w8i;    yii[u][2] = y2r*w8i + y2i*w8r;
    const float y3r = t1r - t3i, y3i = t1i + t3r;
    yrr[u][3] = y3r*w12r - y3i*w12i;  yii[u][3] = y3r*w12i + y3i*w12r;
  }

  // ---- shuffle 2 + fused stage 5 + psd ----
#pragma unroll
  for (int u = 0; u < 4; ++u)
#pragma unroll
    for (int v = 0; v < 4; ++v)
      fc[FI2(gb + u*16 + v*4 + cc)] = make_float2(yrr[u][v], yii[u][v]);

  float psum = 0.f, pmax = 0.f, plog = 0.f;
  const int m0 = t << 4;
#pragma unroll
  for (int q = 0; q < 4; ++q) {
    const float2 z0 = fc[FI2(m0 + q*4 + 0)];
    const float2 z1 = fc[FI2(m0 + q*4 + 1)];
    const float2 z2 = fc[FI2(m0 + q*4 + 2)];
    const float2 z3 = fc[FI2(m0 + q*4 + 3)];
    const float t0r=z0.x+z2.x, t0i=z0.y+z2.y, t1r=z0.x-z2.x, t1i=z0.y-z2.y;
    const float t2r=z1.x+z3.x, t2i=z1.y+z3.y, t3r=z1.x-z3.x, t3i=z1.y-z3.y;
    const float y0r=t0r+t2r, y0i=t0i+t2i;
    const float y1r=t1r+t3i, y1i=t1i-t3r;
    const float y2r=t0r-t2r, y2i=t0i-t2i;
    const float y3r=t1r-t3i, y3i=t1i+t3r;
    const float pp0 = fmaxf(y0r*y0r + y0i*y0i, EPSF);
    const float pp1 = fmaxf(y1r*y1r + y1i*y1i, EPSF);
    const float pp2 = fmaxf(y2r*y2r + y2i*y2i, EPSF);
    const float pp3 = fmaxf(y3r*y3r + y3i*y3i, EPSF);
    psum += pp0 + pp1 + pp2 + pp3;
    pmax = fmaxf(fmaxf(pmax, pp0), fmaxf(pp1, pp2));
    pmax = fmaxf(pmax, pp3);
    plog += pp0*__logf(pp0) + pp1*__logf(pp1) + pp2*__logf(pp2) + pp3*__logf(pp3);
  }
  const float PSUM = rl(wave_red_add(psum), 63);
  const float PMAX = rl(wave_red_max_pos(pmax), 63);
  const float PLOG = rl(wave_red_add(plog), 63);

  // ---- read stashed uniform stats (broadcast LDS reads) ----
  const float SUMSQ = st[0];
  const float ALT   = st[1];
  const float STR   = st[12];
  const float STR2  = st[13];
  const float SC    = st[14];
  const float SC2   = st[15];
  const float SUMX  = st[16];
  const float x0    = st[37];
  const float xl    = st[38];

  // ---- features (uniform across the wave) ----
  const float p0b   = fmaxf(SUMX * SUMX, EPSF);
  const float p512b = fmaxf(ALT * ALT, EPSF);
  const float Sr    = 0.5f * (PSUM + p0b + p512b);
  const float invS  = 1.f / Sr;
  const float PLr   = 0.5f * (PLOG + p0b*__logf(p0b) + p512b*__logf(p512b));
  const float ent   = __logf(Sr) - PLr * invS;

  const float m = SUMX * (1.f / 1024.f);
  const float den = SUMSQ - 1024.f * m * m + EPSF;
  const float invden = 1.f / den;
  float acf1 = 0.f, acf2 = 0.f, lbq = 0.f, R1v = 0.f;
#pragma unroll
  for (int k = 1; k <= 10; ++k) {
    const float Rkv = st[1 + k];
    const float Slo = st[16 + k];     // ps[k]
    const float Shi = st[37 - k];     // ps[1024-k]
    const float num = Rkv - m * (Shi + (SUMX - Slo)) + (float)(1024 - k) * m * m;
    const float a = fminf(fmaxf(num * invden, -1.f), 1.f);
    if (k == 1) { acf1 = a; R1v = Rkv; }
    else if (k == 2) acf2 = a;
    lbq += a * a;
  }
  const float spent = fminf(fmaxf(ent / (__logf(513.f + EPSF) + EPSF), 0.f), 1.f);
  const float peak  = fminf(fmaxf(PMAX / (Sr + EPSF), 0.f), 1.f);
  const float phi = fminf(fmaxf(R1v / ((SUMSQ - xl * xl) + EPSF), -1.f), 1.f);
  const float invn = 1.f / 1023.f;
  const float sum_d2 = 2.f * SUMSQ - x0 * x0 - xl * xl - 2.f * R1v;
  const float md = (xl - x0) * invn;
  const float diff_var = sum_d2 * invn - md * md;
  const float tstr = STR2 * (1.f / 1024.f) - (STR * (1.f / 1024.f)) * (STR * (1.f / 1024.f));
  const float varx = SUMSQ * (1.f / 1024.f) - m * m;
  const float mc = SC * (1.f / 1024.f);
  const float kpss = (SC2 * (1.f / 1024.f) - mc * mc) / (varx + 1e-8f);

  float f[9] = {acf1, acf2, spent, phi, diff_var, tstr, kpss, lbq, peak};
  float fm = 0.f;
#pragma unroll
  for (int d = 0; d < 9; ++d) fm += f[d];
  fm *= (1.f / 9.f);
  float fv = 0.f;
#pragma unroll
  for (int d = 0; d < 9; ++d) { const float tt = f[d] - fm; fv = fmaf(tt, tt, fv); }
  fv *= (1.f / 9.f);
  const float inl = 1.f / sqrtf(fv + 1e-5f);
  float fn[9];
#pragma unroll
  for (int d = 0; d < 9; ++d) fn[d] = (f[d] - fm) * inl * ln_w[d] + ln_b[d];

  // ---- MLP: hidden unit = lane ----
  float h = b1[t];
#pragma unroll
  for (int d = 0; d < 9; ++d) h = fmaf(fn[d], w1[d * 64 + t], h);
  h = fmaxf(h, 0.f);
  float l0 = h * w2[t * 3 + 0];
  float l1 = h * w2[t * 3 + 1];
  float l2 = h * w2[t * 3 + 2];
  l0 = wave_red_add(l0);
  l1 = wave_red_add(l1);
  l2 = wave_red_add(l2);
  const float L0 = rl(l0, 63) + b2[0];
  const float L1 = rl(l1, 63) + b2[1];
  const float L2 = rl(l2, 63) + b2[2];
  if (t == 0) {
    const float mx = fmaxf(L0, fmaxf(L1, L2));
    const float e0 = __expf(L0 - mx), e1 = __expf(L1 - mx), e2 = __expf(L2 - mx);
    const float is = 1.f / (e0 + e1 + e2);
    float* o = out + (size_t)row * 3;
    o[0] = e0 * is; o[1] = e1 * is; o[2] = e2 * is;
    float* fo = out + (size_t)B * 3 + (size_t)row * 9;
    fo[0] = fn[0]; fo[1] = fn[1]; fo[2] = fn[2]; fo[3] = fn[3]; fo[4] = fn[4];
    fo[5] = fn[5]; fo[6] = fn[6]; fo[7] = fn[7]; fo[8] = fn[8];
  }
}

extern "C" void kernel_launch(void* const* d_in, const int* in_sizes, int n_in,
                              void* d_out, int out_size, void* d_ws, size_t ws_size,
                              hipStream_t stream) {
  (void)n_in; (void)out_size; (void)d_ws; (void)ws_size;
  const float* x    = (const float*)d_in[0];
  const float* ln_w = (const float*)d_in[1];
  const float* ln_b = (const float*)d_in[2];
  const float* w1   = (const float*)d_in[3];
  const float* b1   = (const float*)d_in[4];
  const float* w2   = (const float*)d_in[5];
  const float* b2   = (const float*)d_in[6];
  float* out = (float*)d_out;
  const int B = in_sizes[0] / 1024;
  sr_kernel<<<(B + 1) / 2, 128, 0, stream>>>(x, ln_w, ln_b, w1, b1, w2, b2, out, B);
}